// Round 12
// baseline (200.913 us; speedup 1.0000x reference)
//
#include <hip/hip_runtime.h>

#define N_NODES 50000
#define N_EDGES 600000
#define HID 128

typedef __attribute__((ext_vector_type(8))) short short8;
typedef __attribute__((ext_vector_type(4))) float f32x4;

__device__ __forceinline__ unsigned short f2bf(float f) {
    unsigned u = __float_as_uint(f);
    unsigned r = u + 0x7FFFu + ((u >> 16) & 1u);  // RNE
    return (unsigned short)(r >> 16);
}
__device__ __forceinline__ float bf2f(unsigned short h) {
    return __uint_as_float(((unsigned)h) << 16);
}

// gelu(tanh approx) == x / (1 + exp(-2u)), u = 0.79788456*(x + 0.044715 x^3)
__device__ __forceinline__ float gelu_fast(float x) {
    float u = 0.7978845608028654f * (x + 0.044715f * x * x * x);
    return x / (1.0f + __expf(-2.0f * u));
}

// ---------------------------------------------------------------------------
// prep: weight pack (hi-only bf16) + zero deg/cursor + x f32->bf16.
// Pack layout (verified R3-R11): n = nt*16+(lane&15), k = ks*32+(lane>>4)*8+j.
// ---------------------------------------------------------------------------
#define PACK_BLOCKS 512          // 6 x 64 + 128 (Wlin)
#define ZERO_BLOCKS 49           // 12501 int4 = deg(50000)+cursor(4)
#define CVT_BLOCKS  3125         // 50000*128/8/256
__global__ void prep(const float* __restrict__ x, unsigned short* __restrict__ xbf,
                     const float* __restrict__ Wp1, const float* __restrict__ Wl1,
                     const float* __restrict__ Wr1, const float* __restrict__ Wp2,
                     const float* __restrict__ Wl2, const float* __restrict__ Wr2,
                     const float* __restrict__ Wlin, unsigned short* __restrict__ wpack,
                     int* __restrict__ zbase) {
    int b = blockIdx.x;
    if (b < PACK_BLOCKS) {
        const float* W;
        int base, idx;
        if (b < 384) {
            int which = b >> 6;
            switch (which) {
                case 0: W = Wp1; break;
                case 1: W = Wl1; break;
                case 2: W = Wr1; break;
                case 3: W = Wp2; break;
                case 4: W = Wl2; break;
                default: W = Wr2; break;
            }
            base = which * 16384;
            idx = (b & 63) * 256 + threadIdx.x;
        } else {
            W = Wlin;
            base = 98304;
            idx = (b - 384) * 256 + threadIdx.x;
        }
        int j = idx & 7;
        int lane = (idx >> 3) & 63;
        int ks = (idx >> 9) & 3;
        int nt = idx >> 11;
        int c = nt * 16 + (lane & 15);
        int k = ks * 32 + (lane >> 4) * 8 + j;
        wpack[base + idx] = f2bf(W[c * 128 + k]);
    } else if (b < PACK_BLOCKS + ZERO_BLOCKS) {
        int i = (b - PACK_BLOCKS) * 256 + threadIdx.x;
        if (i < 12501) ((int4*)zbase)[i] = make_int4(0, 0, 0, 0);
    } else {
        int tid = (b - PACK_BLOCKS - ZERO_BLOCKS) * 256 + threadIdx.x;
        size_t i8 = (size_t)tid * 8;
        if (i8 >= (size_t)N_NODES * HID) return;
        float4 v0 = *(const float4*)(x + i8);
        float4 v1 = *(const float4*)(x + i8 + 4);
        short8 o;
        o[0] = f2bf(v0.x); o[1] = f2bf(v0.y); o[2] = f2bf(v0.z); o[3] = f2bf(v0.w);
        o[4] = f2bf(v1.x); o[5] = f2bf(v1.y); o[6] = f2bf(v1.z); o[7] = f2bf(v1.w);
        *(short8*)(xbf + i8) = o;
    }
}

// count + rank: rank[e] = arrival order within dst segment.
__global__ void count_rank(const int* __restrict__ ei, int* __restrict__ deg,
                           int* __restrict__ rank) {
    int e = blockIdx.x * 256 + threadIdx.x;
    if (e < N_EDGES) {
        int dst = ei[N_EDGES + e];
        rank[e] = atomicAdd(&deg[dst], 1);
    }
}

// One-kernel exclusive scan via atomic cursor (order-invariant downstream).
__global__ void build_off(const int* __restrict__ deg, int* __restrict__ off,
                          int* __restrict__ cursor) {
    __shared__ int sm[256];
    __shared__ int base;
    int t = threadIdx.x;
    int i = blockIdx.x * 256 + t;
    int v = (i < N_NODES) ? deg[i] : 0;
    sm[t] = v;
    __syncthreads();
    for (int s = 1; s < 256; s <<= 1) {
        int tv = (t >= s) ? sm[t - s] : 0;
        __syncthreads();
        sm[t] += tv;
        __syncthreads();
    }
    if (t == 255) base = atomicAdd(cursor, sm[255]);
    __syncthreads();
    if (i < N_NODES) off[i] = base + sm[t] - v;
}

// ---------------------------------------------------------------------------
// combo (R11): block-role split {csr-fill | edge echo | lin1} in ONE launch.
// ---------------------------------------------------------------------------
#define FB   2344   // fill blocks (600000/256)
#define EB4  1172   // echo blocks (1200000/4/256)
#define LB   1563   // lin1 blocks (50000/32)
__global__ __launch_bounds__(256, 2) void combo(
        const int* __restrict__ ei, const int* __restrict__ off,
        const int* __restrict__ rank, int* __restrict__ csr,
        float* __restrict__ echo,
        const unsigned short* __restrict__ in1, const unsigned short* __restrict__ B1,
        const float* __restrict__ bias1, unsigned short* __restrict__ out1) {
    int b = blockIdx.x;
    int t = threadIdx.x;
    if (b < FB) {
        int e = b * 256 + t;
        if (e < N_EDGES) {
            int dst = ei[N_EDGES + e];
            csr[off[dst] + rank[e]] = ei[e];
        }
        return;
    }
    if (b < FB + EB4) {
        int idx = (b - FB) * 256 + t;
        int i = idx * 4;
        if (i < 2 * N_EDGES) {
            int4 v = *(const int4*)(ei + i);
            float4 f = make_float4((float)v.x, (float)v.y, (float)v.z, (float)v.w);
            *(float4*)(echo + i) = f;
        }
        return;
    }
    {
        __shared__ alignas(16) unsigned short hA[32][128];
        const int bid = b - FB - EB4;
        const int w = t >> 6;
        const int l = t & 63;
        const int blockRow = bid * 32;

        int r0 = blockRow + (l & 15);
        int r1 = r0 + 16;
        if (r0 > N_NODES - 1) r0 = N_NODES - 1;
        if (r1 > N_NODES - 1) r1 = N_NODES - 1;
        const int ko = (l >> 4) * 8;

        short8 a1[2][4];
#pragma unroll
        for (int ks = 0; ks < 4; ++ks) {
            a1[0][ks] = *(const short8*)(in1 + (size_t)r0 * HID + ks * 32 + ko);
            a1[1][ks] = *(const short8*)(in1 + (size_t)r1 * HID + ks * 32 + ko);
        }
        const int cL = l & 15;
        const int rfrag = (l >> 4) * 4;

        short8 b1r[3];
        const size_t gb = (size_t)(w * 8) * 64 + l;
        b1r[0] = *(const short8*)(B1 + (gb + 0 * 64) * 8);
        b1r[1] = *(const short8*)(B1 + (gb + 1 * 64) * 8);
#pragma unroll
        for (int m = 0; m < 2; ++m) {
            const int nt = w * 2 + m;
            f32x4 acc0 = {0.f, 0.f, 0.f, 0.f};
            f32x4 acc1 = {0.f, 0.f, 0.f, 0.f};
#pragma unroll
            for (int ks = 0; ks < 4; ++ks) {
                const int step = m * 4 + ks;
                const int cur = step % 3;
                if (step + 2 < 8)
                    b1r[(step + 2) % 3] = *(const short8*)(B1 + (gb + (size_t)(step + 2) * 64) * 8);
                acc0 = __builtin_amdgcn_mfma_f32_16x16x32_bf16(a1[0][ks], b1r[cur], acc0, 0, 0, 0);
                acc1 = __builtin_amdgcn_mfma_f32_16x16x32_bf16(a1[1][ks], b1r[cur], acc1, 0, 0, 0);
            }
            float bc = bias1[nt * 16 + cL];
#pragma unroll
            for (int reg = 0; reg < 4; ++reg) {
                int rl = rfrag + reg;
                int cs = (nt * 16 + cL) ^ ((rl & 7) << 3);
                hA[rl][cs] = f2bf(acc0[reg] + bc);
                hA[rl + 16][cs] = f2bf(acc1[reg] + bc);
            }
        }
        __syncthreads();
#pragma unroll
        for (int p = 0; p < 2; ++p) {
            int idx = p * 256 + t;
            int row = idx >> 4;
            int c0 = (idx & 15) * 8;
            int cs0 = c0 ^ ((row & 7) << 3);
            short8 v = *(const short8*)&hA[row][cs0];
            int grow = blockRow + row;
            if (grow < N_NODES)
                *(short8*)(out1 + (size_t)grow * HID + c0) = v;
        }
    }
}

// ---------------------------------------------------------------------------
// seg_fused (R12): per-block {seg-max gather -> LDS aggT} + dual GEMM +
// fused second stage. Eliminates the agg global round-trip (12.8MB write +
// 12.8MB read per layer) and both seg_max launches. agg values are exact
// bf16 maxima -> arithmetic bit-identical to the split version.
// Seg phase: wave w gathers nodes blockRow + w*8 .. +7 (lane owns 2 cols),
// writes swizzled aggT[32][128]. Stage 1: A1-frags from aggT (LDS), A2 from
// global in2. Stage 2: as R11 (hA -> hB bf16 or fT f32).
// ---------------------------------------------------------------------------
template <bool STORE1, int NT2, int ACT2, bool OBF2>
__global__ __launch_bounds__(256, 2) void seg_fused(
        const unsigned short* __restrict__ y, const int* __restrict__ csr,
        const int* __restrict__ off, const int* __restrict__ deg,
        const unsigned short* __restrict__ in2,
        const unsigned short* __restrict__ B1, const unsigned short* __restrict__ B2,
        const float* __restrict__ bias1, unsigned short* __restrict__ out1,
        const unsigned short* __restrict__ B3, const float* __restrict__ bias3,
        void* __restrict__ out2) {
    __shared__ alignas(16) unsigned short aggT[32][128];
    __shared__ alignas(16) unsigned short hA[32][128];
    __shared__ alignas(16) unsigned short hB[OBF2 ? 32 : 1][128];
    __shared__ alignas(16) float fT[OBF2 ? 1 : 32][132];

    const int t = threadIdx.x;
    const int w = t >> 6;
    const int l = t & 63;
    const int blockRow = blockIdx.x * 32;

    // ---- seg phase: wave w -> local rows w*8 .. w*8+7 ----
    {
        const unsigned short* yb = y + l * 2;
#pragma unroll
        for (int j = 0; j < 8; ++j) {
            int lr = w * 8 + j;
            int n = blockRow + lr;
            if (n > N_NODES - 1) n = N_NODES - 1;
            int s = off[n];
            int d = deg[n];
            float a0 = 0.f, a1v = 0.f;
            int i = 0;
            for (; i + 4 <= d; i += 4) {
                int s0 = csr[s + i], s1 = csr[s + i + 1];
                int s2 = csr[s + i + 2], s3 = csr[s + i + 3];
                unsigned v0 = *(const unsigned*)(yb + (size_t)s0 * HID);
                unsigned v1 = *(const unsigned*)(yb + (size_t)s1 * HID);
                unsigned v2 = *(const unsigned*)(yb + (size_t)s2 * HID);
                unsigned v3 = *(const unsigned*)(yb + (size_t)s3 * HID);
                a0 = fmaxf(a0, fmaxf(fmaxf(__uint_as_float(v0 << 16), __uint_as_float(v1 << 16)),
                                     fmaxf(__uint_as_float(v2 << 16), __uint_as_float(v3 << 16))));
                a1v = fmaxf(a1v, fmaxf(fmaxf(__uint_as_float(v0 & 0xffff0000u), __uint_as_float(v1 & 0xffff0000u)),
                                       fmaxf(__uint_as_float(v2 & 0xffff0000u), __uint_as_float(v3 & 0xffff0000u))));
            }
            for (; i < d; ++i) {
                int s0 = csr[s + i];
                unsigned v0 = *(const unsigned*)(yb + (size_t)s0 * HID);
                a0 = fmaxf(a0, __uint_as_float(v0 << 16));
                a1v = fmaxf(a1v, __uint_as_float(v0 & 0xffff0000u));
            }
            unsigned o = (unsigned)f2bf(a0) | ((unsigned)f2bf(a1v) << 16);
            int cs = (l * 2) ^ ((lr & 7) << 3);  // pair-preserving XOR swizzle
            *(unsigned*)&aggT[lr][cs] = o;
        }
    }
    __syncthreads();

    // ---- stage-1 operand fragments: A1 from aggT (LDS), A2 from global ----
    const int ko = (l >> 4) * 8;
    const int cL = l & 15;
    const int rfrag = (l >> 4) * 4;
    const int rA = l & 15;

    int r0 = blockRow + rA;
    int r1 = r0 + 16;
    if (r0 > N_NODES - 1) r0 = N_NODES - 1;
    if (r1 > N_NODES - 1) r1 = N_NODES - 1;

    short8 a1[2][4], a2[2][4];
#pragma unroll
    for (int ks = 0; ks < 4; ++ks) {
        int b0 = (ks * 32 + ko) ^ ((rA & 7) << 3);
        a1[0][ks] = *(const short8*)&aggT[rA][b0];
        a1[1][ks] = *(const short8*)&aggT[rA + 16][b0];
        a2[0][ks] = *(const short8*)(in2 + (size_t)r0 * HID + ks * 32 + ko);
        a2[1][ks] = *(const short8*)(in2 + (size_t)r1 * HID + ks * 32 + ko);
    }

    // ---- stage 1 dual GEMM (MY1=2 -> 8 steps), depth-2 B ring, gelu ----
    {
        short8 b1r[3], b2r[3];
        const size_t gb = (size_t)(w * 8) * 64 + l;
        b1r[0] = *(const short8*)(B1 + (gb + 0 * 64) * 8);
        b2r[0] = *(const short8*)(B2 + (gb + 0 * 64) * 8);
        b1r[1] = *(const short8*)(B1 + (gb + 1 * 64) * 8);
        b2r[1] = *(const short8*)(B2 + (gb + 1 * 64) * 8);
#pragma unroll
        for (int m = 0; m < 2; ++m) {
            const int nt = w * 2 + m;
            f32x4 acc0 = {0.f, 0.f, 0.f, 0.f};
            f32x4 acc1 = {0.f, 0.f, 0.f, 0.f};
#pragma unroll
            for (int ks = 0; ks < 4; ++ks) {
                const int step = m * 4 + ks;
                const int cur = step % 3;
                if (step + 2 < 8) {
                    const int s2 = (step + 2) % 3;
                    b1r[s2] = *(const short8*)(B1 + (gb + (size_t)(step + 2) * 64) * 8);
                    b2r[s2] = *(const short8*)(B2 + (gb + (size_t)(step + 2) * 64) * 8);
                }
                acc0 = __builtin_amdgcn_mfma_f32_16x16x32_bf16(a1[0][ks], b1r[cur], acc0, 0, 0, 0);
                acc1 = __builtin_amdgcn_mfma_f32_16x16x32_bf16(a1[1][ks], b1r[cur], acc1, 0, 0, 0);
                acc0 = __builtin_amdgcn_mfma_f32_16x16x32_bf16(a2[0][ks], b2r[cur], acc0, 0, 0, 0);
                acc1 = __builtin_amdgcn_mfma_f32_16x16x32_bf16(a2[1][ks], b2r[cur], acc1, 0, 0, 0);
            }
            float bc = bias1[nt * 16 + cL];
#pragma unroll
            for (int reg = 0; reg < 4; ++reg) {
                float v0 = gelu_fast(acc0[reg] + bc);
                float v1 = gelu_fast(acc1[reg] + bc);
                int rl = rfrag + reg;
                int cs = (nt * 16 + cL) ^ ((rl & 7) << 3);
                hA[rl][cs] = f2bf(v0);
                hA[rl + 16][cs] = f2bf(v1);
            }
        }
    }
    __syncthreads();

    if (STORE1) {
#pragma unroll
        for (int p = 0; p < 2; ++p) {
            int idx = p * 256 + t;
            int row = idx >> 4;
            int c0 = (idx & 15) * 8;
            int cs0 = c0 ^ ((row & 7) << 3);
            short8 v = *(const short8*)&hA[row][cs0];
            int grow = blockRow + row;
            if (grow < N_NODES)
                *(short8*)(out1 + (size_t)grow * HID + c0) = v;
        }
    }

    // ---- stage 2: A-frags from hA ----
    short8 c1[2][4];
#pragma unroll
    for (int ks = 0; ks < 4; ++ks) {
        int b0 = (ks * 32 + ko) ^ ((rA & 7) << 3);
        c1[0][ks] = *(const short8*)&hA[rA][b0];
        c1[1][ks] = *(const short8*)&hA[rA + 16][b0];
    }
    if (OBF2) {
        short8 b1r[3];
        const size_t gb = (size_t)(w * 8) * 64 + l;
        b1r[0] = *(const short8*)(B3 + (gb + 0 * 64) * 8);
        b1r[1] = *(const short8*)(B3 + (gb + 1 * 64) * 8);
#pragma unroll
        for (int m = 0; m < 2; ++m) {
            const int nt = w * 2 + m;
            f32x4 acc0 = {0.f, 0.f, 0.f, 0.f};
            f32x4 acc1 = {0.f, 0.f, 0.f, 0.f};
#pragma unroll
            for (int ks = 0; ks < 4; ++ks) {
                const int step = m * 4 + ks;
                const int cur = step % 3;
                if (step + 2 < 8)
                    b1r[(step + 2) % 3] = *(const short8*)(B3 + (gb + (size_t)(step + 2) * 64) * 8);
                acc0 = __builtin_amdgcn_mfma_f32_16x16x32_bf16(c1[0][ks], b1r[cur], acc0, 0, 0, 0);
                acc1 = __builtin_amdgcn_mfma_f32_16x16x32_bf16(c1[1][ks], b1r[cur], acc1, 0, 0, 0);
            }
            float bc = bias3[nt * 16 + cL];
#pragma unroll
            for (int reg = 0; reg < 4; ++reg) {
                float v0 = acc0[reg] + bc;
                float v1 = acc1[reg] + bc;
                if (ACT2 == 1) { v0 = gelu_fast(v0); v1 = gelu_fast(v1); }
                int rl = rfrag + reg;
                int cs = (nt * 16 + cL) ^ ((rl & 7) << 3);
                hB[rl][cs] = f2bf(v0);
                hB[rl + 16][cs] = f2bf(v1);
            }
        }
        __syncthreads();
#pragma unroll
        for (int p = 0; p < 2; ++p) {
            int idx = p * 256 + t;
            int row = idx >> 4;
            int c0 = (idx & 15) * 8;
            int cs0 = c0 ^ ((row & 7) << 3);
            short8 v = *(const short8*)&hB[row][cs0];
            int grow = blockRow + row;
            if (grow < N_NODES)
                *(short8*)((unsigned short*)out2 + (size_t)grow * (NT2 * 16) + c0) = v;
        }
    } else {
        // f32 out (NT2=16, 256 cols) in two column-halves via fT
#pragma unroll
        for (int h = 0; h < 2; ++h) {
            const int ntb = h * 8 + w * 2;
            short8 b1r[3];
            const size_t gb = (size_t)(ntb * 4) * 64 + l;
            b1r[0] = *(const short8*)(B3 + (gb + 0 * 64) * 8);
            b1r[1] = *(const short8*)(B3 + (gb + 1 * 64) * 8);
#pragma unroll
            for (int m = 0; m < 2; ++m) {
                const int nt = ntb + m;
                f32x4 acc0 = {0.f, 0.f, 0.f, 0.f};
                f32x4 acc1 = {0.f, 0.f, 0.f, 0.f};
#pragma unroll
                for (int ks = 0; ks < 4; ++ks) {
                    const int step = m * 4 + ks;
                    const int cur = step % 3;
                    if (step + 2 < 8)
                        b1r[(step + 2) % 3] = *(const short8*)(B3 + (gb + (size_t)(step + 2) * 64) * 8);
                    acc0 = __builtin_amdgcn_mfma_f32_16x16x32_bf16(c1[0][ks], b1r[cur], acc0, 0, 0, 0);
                    acc1 = __builtin_amdgcn_mfma_f32_16x16x32_bf16(c1[1][ks], b1r[cur], acc1, 0, 0, 0);
                }
                float bc = bias3[nt * 16 + cL];
                int ct = (nt - h * 8) * 16 + cL;
#pragma unroll
                for (int reg = 0; reg < 4; ++reg) {
                    float v0 = acc0[reg] + bc;
                    float v1 = acc1[reg] + bc;
                    if (ACT2 == 1) { v0 = gelu_fast(v0); v1 = gelu_fast(v1); }
                    fT[rfrag + reg][ct] = v0;
                    fT[rfrag + reg + 16][ct] = v1;
                }
            }
            __syncthreads();
#pragma unroll
            for (int p = 0; p < 4; ++p) {
                int idx = p * 256 + t;
                int row = idx >> 5;
                int s4 = (idx & 31) * 4;
                float4 v = *(const float4*)&fT[row][s4];
                int grow = blockRow + row;
                if (grow < N_NODES)
                    *(float4*)((float*)out2 + (size_t)grow * 256 + h * 128 + s4) = v;
            }
            __syncthreads();
        }
    }
}

extern "C" void kernel_launch(void* const* d_in, const int* in_sizes, int n_in,
                              void* d_out, int out_size, void* d_ws, size_t ws_size,
                              hipStream_t stream) {
    const float* x    = (const float*)d_in[0];
    const int*   ei   = (const int*)d_in[1];
    const float* Wp1  = (const float*)d_in[2];
    const float* bp1  = (const float*)d_in[3];
    const float* Wl1  = (const float*)d_in[4];
    const float* bl1  = (const float*)d_in[5];
    const float* Wr1  = (const float*)d_in[6];
    const float* Wp2  = (const float*)d_in[7];
    const float* bp2  = (const float*)d_in[8];
    const float* Wl2  = (const float*)d_in[9];
    const float* bl2  = (const float*)d_in[10];
    const float* Wr2  = (const float*)d_in[11];
    const float* Wlin = (const float*)d_in[12];
    const float* blin = (const float*)d_in[13];
    float* out = (float*)d_out;

    // ws layout (ushort units for bf16 region); wpack hi-only = 131072
    unsigned short* wpack = (unsigned short*)d_ws;
    unsigned short* xbf   = wpack + 131072;
    unsigned short* ybf   = xbf + (size_t)N_NODES * HID;   // y1 / y2
    unsigned short* h1bf  = ybf + (size_t)N_NODES * HID;   // h1
    int* deg    = (int*)(h1bf + (size_t)N_NODES * HID);    // 50000
    int* cursor = deg + N_NODES;                            // 4 (zeroed w/ deg)
    int* off    = cursor + 4;                               // 50000
    int* rank   = off + N_NODES;                            // 600000
    int* csr    = rank + N_EDGES;                           // 600000

    const unsigned short* Bp1 = wpack + 0;
    const unsigned short* Bl1 = wpack + 16384;
    const unsigned short* Br1 = wpack + 32768;
    const unsigned short* Bp2 = wpack + 49152;
    const unsigned short* Bl2 = wpack + 65536;
    const unsigned short* Br2 = wpack + 81920;
    const unsigned short* Blin = wpack + 98304;

    const int RB32 = (N_NODES + 31) / 32;   // 1563
    const int NPB  = (N_NODES + 255) / 256; // 196

    // 1. prep: pack weights + zero deg/cursor + convert x
    hipLaunchKernelGGL(prep, dim3(PACK_BLOCKS + ZERO_BLOCKS + CVT_BLOCKS), dim3(256), 0, stream,
                       x, xbf, Wp1, Wl1, Wr1, Wp2, Wl2, Wr2, Wlin, wpack, deg);

    // 2. count + rank
    hipLaunchKernelGGL(count_rank, dim3((N_EDGES + 255) / 256), dim3(256), 0, stream,
                       ei, deg, rank);

    // 3. offsets
    hipLaunchKernelGGL(build_off, dim3(NPB), dim3(256), 0, stream, deg, off, cursor);

    // 4. combo: csr-fill + edge-echo + lin1 (y1 = xbf@Wp1 + bp1), overlapped
    hipLaunchKernelGGL(combo, dim3(FB + EB4 + LB), dim3(256), 0, stream,
                       ei, off, rank, csr, out + (size_t)N_NODES * 256,
                       xbf, Bp1, bp1, ybf);

    // 5. seg1 + {h1 = gelu(agg@Wl1 + x@Wr1 + bl1) [store]; y2 = h1@Wp2 + bp2}
    hipLaunchKernelGGL((seg_fused<true, 8, 0, true>), dim3(RB32), dim3(256), 0, stream,
                       ybf, csr, off, deg, xbf, Bl1, Br1, bl1, h1bf, Bp2, bp2, ybf);

    // 6. seg2 + {h2 = gelu(agg@Wl2 + h1@Wr2 + bl2); out = gelu(h2@Wlin + blin) f32}
    hipLaunchKernelGGL((seg_fused<false, 16, 1, false>), dim3(RB32), dim3(256), 0, stream,
                       ybf, csr, off, deg, h1bf, Bl2, Br2, bl2, nullptr, Blin, blin, out);
}

// Round 13
// 181.163 us; speedup vs baseline: 1.1090x; 1.1090x over previous
//
#include <hip/hip_runtime.h>

#define N_NODES 50000
#define N_EDGES 600000
#define HID 128

typedef __attribute__((ext_vector_type(8))) short short8;
typedef __attribute__((ext_vector_type(4))) float f32x4;

__device__ __forceinline__ unsigned short f2bf(float f) {
    unsigned u = __float_as_uint(f);
    unsigned r = u + 0x7FFFu + ((u >> 16) & 1u);  // RNE
    return (unsigned short)(r >> 16);
}
__device__ __forceinline__ float bf2f(unsigned short h) {
    return __uint_as_float(((unsigned)h) << 16);
}

// gelu(tanh approx) == x / (1 + exp(-2u)), u = 0.79788456*(x + 0.044715 x^3)
__device__ __forceinline__ float gelu_fast(float x) {
    float u = 0.7978845608028654f * (x + 0.044715f * x * x * x);
    return x / (1.0f + __expf(-2.0f * u));
}

// R12 ERRATA: merging seg_max into the fused GEMM raced (out2 buffer == seg
// input buffer across concurrent blocks) and collapsed gather TLP (50000 ->
// 6252 waves). Reverted to the R11 split; launch boundary = the sync.

// zero deg+cursor (runs before prep so prep's count-role can atomicAdd)
__global__ void zero_deg(int* __restrict__ zbase) {
    int i = blockIdx.x * 256 + threadIdx.x;
    if (i < 12501) ((int4*)zbase)[i] = make_int4(0, 0, 0, 0);
}

// ---------------------------------------------------------------------------
// prep: role-split {weight pack | x cvt | count+rank} in ONE launch.
// Pack layout (verified R3-R11): n = nt*16+(lane&15), k = ks*32+(lane>>4)*8+j.
// ---------------------------------------------------------------------------
#define PACK_BLOCKS 512          // 6 x 64 + 128 (Wlin)
#define CVT_BLOCKS  3125         // 50000*128/8/256
#define CNT_BLOCKS  2344         // 600000/256
__global__ void prep(const float* __restrict__ x, unsigned short* __restrict__ xbf,
                     const float* __restrict__ Wp1, const float* __restrict__ Wl1,
                     const float* __restrict__ Wr1, const float* __restrict__ Wp2,
                     const float* __restrict__ Wl2, const float* __restrict__ Wr2,
                     const float* __restrict__ Wlin, unsigned short* __restrict__ wpack,
                     const int* __restrict__ ei, int* __restrict__ deg,
                     int* __restrict__ rank) {
    int b = blockIdx.x;
    if (b < PACK_BLOCKS) {
        const float* W;
        int base, idx;
        if (b < 384) {
            int which = b >> 6;
            switch (which) {
                case 0: W = Wp1; break;
                case 1: W = Wl1; break;
                case 2: W = Wr1; break;
                case 3: W = Wp2; break;
                case 4: W = Wl2; break;
                default: W = Wr2; break;
            }
            base = which * 16384;
            idx = (b & 63) * 256 + threadIdx.x;
        } else {
            W = Wlin;
            base = 98304;
            idx = (b - 384) * 256 + threadIdx.x;
        }
        int j = idx & 7;
        int lane = (idx >> 3) & 63;
        int ks = (idx >> 9) & 3;
        int nt = idx >> 11;
        int c = nt * 16 + (lane & 15);
        int k = ks * 32 + (lane >> 4) * 8 + j;
        wpack[base + idx] = f2bf(W[c * 128 + k]);
    } else if (b < PACK_BLOCKS + CVT_BLOCKS) {
        int tid = (b - PACK_BLOCKS) * 256 + threadIdx.x;
        size_t i8 = (size_t)tid * 8;
        if (i8 >= (size_t)N_NODES * HID) return;
        float4 v0 = *(const float4*)(x + i8);
        float4 v1 = *(const float4*)(x + i8 + 4);
        short8 o;
        o[0] = f2bf(v0.x); o[1] = f2bf(v0.y); o[2] = f2bf(v0.z); o[3] = f2bf(v0.w);
        o[4] = f2bf(v1.x); o[5] = f2bf(v1.y); o[6] = f2bf(v1.z); o[7] = f2bf(v1.w);
        *(short8*)(xbf + i8) = o;
    } else {
        // count + rank (deg zeroed by the preceding zero_deg launch)
        int e = (b - PACK_BLOCKS - CVT_BLOCKS) * 256 + threadIdx.x;
        if (e < N_EDGES) {
            int dst = ei[N_EDGES + e];
            rank[e] = atomicAdd(&deg[dst], 1);
        }
    }
}

// One-kernel exclusive scan via atomic cursor (order-invariant downstream).
__global__ void build_off(const int* __restrict__ deg, int* __restrict__ off,
                          int* __restrict__ cursor) {
    __shared__ int sm[256];
    __shared__ int base;
    int t = threadIdx.x;
    int i = blockIdx.x * 256 + t;
    int v = (i < N_NODES) ? deg[i] : 0;
    sm[t] = v;
    __syncthreads();
    for (int s = 1; s < 256; s <<= 1) {
        int tv = (t >= s) ? sm[t - s] : 0;
        __syncthreads();
        sm[t] += tv;
        __syncthreads();
    }
    if (t == 255) base = atomicAdd(cursor, sm[255]);
    __syncthreads();
    if (i < N_NODES) off[i] = base + sm[t] - v;
}

// ---------------------------------------------------------------------------
// combo: block-role split {csr-fill | edge echo | lin1} in ONE launch.
// lin1 now issues all 8 B-step loads upfront (R13).
// ---------------------------------------------------------------------------
#define FB   2344   // fill blocks (600000/256)
#define EB4  1172   // echo blocks (1200000/4/256)
#define LB   1563   // lin1 blocks (50000/32)
__global__ __launch_bounds__(256, 2) void combo(
        const int* __restrict__ ei, const int* __restrict__ off,
        const int* __restrict__ rank, int* __restrict__ csr,
        float* __restrict__ echo,
        const unsigned short* __restrict__ in1, const unsigned short* __restrict__ B1,
        const float* __restrict__ bias1, unsigned short* __restrict__ out1) {
    int b = blockIdx.x;
    int t = threadIdx.x;
    if (b < FB) {
        int e = b * 256 + t;
        if (e < N_EDGES) {
            int dst = ei[N_EDGES + e];
            csr[off[dst] + rank[e]] = ei[e];
        }
        return;
    }
    if (b < FB + EB4) {
        int idx = (b - FB) * 256 + t;
        int i = idx * 4;
        if (i < 2 * N_EDGES) {
            int4 v = *(const int4*)(ei + i);
            float4 f = make_float4((float)v.x, (float)v.y, (float)v.z, (float)v.w);
            *(float4*)(echo + i) = f;
        }
        return;
    }
    {
        __shared__ alignas(16) unsigned short hA[32][128];
        const int bid = b - FB - EB4;
        const int w = t >> 6;
        const int l = t & 63;
        const int blockRow = bid * 32;

        int r0 = blockRow + (l & 15);
        int r1 = r0 + 16;
        if (r0 > N_NODES - 1) r0 = N_NODES - 1;
        if (r1 > N_NODES - 1) r1 = N_NODES - 1;
        const int ko = (l >> 4) * 8;

        short8 a1[2][4];
#pragma unroll
        for (int ks = 0; ks < 4; ++ks) {
            a1[0][ks] = *(const short8*)(in1 + (size_t)r0 * HID + ks * 32 + ko);
            a1[1][ks] = *(const short8*)(in1 + (size_t)r1 * HID + ks * 32 + ko);
        }
        const int cL = l & 15;
        const int rfrag = (l >> 4) * 4;

        // all 8 B-step loads upfront (latency paid once)
        short8 b1v[8];
        const size_t gb = (size_t)(w * 8) * 64 + l;
#pragma unroll
        for (int s = 0; s < 8; ++s)
            b1v[s] = *(const short8*)(B1 + (gb + (size_t)s * 64) * 8);

#pragma unroll
        for (int m = 0; m < 2; ++m) {
            const int nt = w * 2 + m;
            f32x4 acc0 = {0.f, 0.f, 0.f, 0.f};
            f32x4 acc1 = {0.f, 0.f, 0.f, 0.f};
#pragma unroll
            for (int ks = 0; ks < 4; ++ks) {
                const int step = m * 4 + ks;
                acc0 = __builtin_amdgcn_mfma_f32_16x16x32_bf16(a1[0][ks], b1v[step], acc0, 0, 0, 0);
                acc1 = __builtin_amdgcn_mfma_f32_16x16x32_bf16(a1[1][ks], b1v[step], acc1, 0, 0, 0);
            }
            float bc = bias1[nt * 16 + cL];
#pragma unroll
            for (int reg = 0; reg < 4; ++reg) {
                int rl = rfrag + reg;
                int cs = (nt * 16 + cL) ^ ((rl & 7) << 3);
                hA[rl][cs] = f2bf(acc0[reg] + bc);
                hA[rl + 16][cs] = f2bf(acc1[reg] + bc);
            }
        }
        __syncthreads();
#pragma unroll
        for (int p = 0; p < 2; ++p) {
            int idx = p * 256 + t;
            int row = idx >> 4;
            int c0 = (idx & 15) * 8;
            int cs0 = c0 ^ ((row & 7) << 3);
            short8 v = *(const short8*)&hA[row][cs0];
            int grow = blockRow + row;
            if (grow < N_NODES)
                *(short8*)(out1 + (size_t)grow * HID + c0) = v;
        }
    }
}

// ---------------------------------------------------------------------------
// Fused dual-GEMM + second stage (1-term bf16, upfront B loads).
// ---------------------------------------------------------------------------
template <bool STORE1, int NT2, int ACT2, bool OBF2>
__global__ __launch_bounds__(256, 2) void mfma_fused(
        const unsigned short* __restrict__ in1, const unsigned short* __restrict__ in2,
        const unsigned short* __restrict__ B1, const unsigned short* __restrict__ B2,
        const float* __restrict__ bias1, void* __restrict__ out1,
        const unsigned short* __restrict__ B3, const float* __restrict__ bias3,
        void* __restrict__ out2) {
    __shared__ alignas(16) unsigned short hA[32][128];
    __shared__ alignas(16) unsigned short hB[OBF2 ? 32 : 1][128];
    __shared__ alignas(16) float fT[OBF2 ? 1 : 32][132];

    const int t = threadIdx.x;
    const int w = t >> 6;
    const int l = t & 63;
    const int blockRow = blockIdx.x * 32;

    int r0 = blockRow + (l & 15);
    int r1 = r0 + 16;
    if (r0 > N_NODES - 1) r0 = N_NODES - 1;
    if (r1 > N_NODES - 1) r1 = N_NODES - 1;
    const int ko = (l >> 4) * 8;

    short8 a1[2][4], a2[2][4];
#pragma unroll
    for (int ks = 0; ks < 4; ++ks) {
        a1[0][ks] = *(const short8*)(in1 + (size_t)r0 * HID + ks * 32 + ko);
        a1[1][ks] = *(const short8*)(in1 + (size_t)r1 * HID + ks * 32 + ko);
        a2[0][ks] = *(const short8*)(in2 + (size_t)r0 * HID + ks * 32 + ko);
        a2[1][ks] = *(const short8*)(in2 + (size_t)r1 * HID + ks * 32 + ko);
    }
    const int cL = l & 15;
    const int rfrag = (l >> 4) * 4;

    // ---- stage 1 dual GEMM: all 16 B loads upfront ----
    {
        short8 b1v[8], b2v[8];
        const size_t gb = (size_t)(w * 8) * 64 + l;
#pragma unroll
        for (int s = 0; s < 8; ++s) {
            b1v[s] = *(const short8*)(B1 + (gb + (size_t)s * 64) * 8);
            b2v[s] = *(const short8*)(B2 + (gb + (size_t)s * 64) * 8);
        }
#pragma unroll
        for (int m = 0; m < 2; ++m) {
            const int nt = w * 2 + m;
            f32x4 acc0 = {0.f, 0.f, 0.f, 0.f};
            f32x4 acc1 = {0.f, 0.f, 0.f, 0.f};
#pragma unroll
            for (int ks = 0; ks < 4; ++ks) {
                const int step = m * 4 + ks;
                acc0 = __builtin_amdgcn_mfma_f32_16x16x32_bf16(a1[0][ks], b1v[step], acc0, 0, 0, 0);
                acc1 = __builtin_amdgcn_mfma_f32_16x16x32_bf16(a1[1][ks], b1v[step], acc1, 0, 0, 0);
                acc0 = __builtin_amdgcn_mfma_f32_16x16x32_bf16(a2[0][ks], b2v[step], acc0, 0, 0, 0);
                acc1 = __builtin_amdgcn_mfma_f32_16x16x32_bf16(a2[1][ks], b2v[step], acc1, 0, 0, 0);
            }
            float bc = bias1[nt * 16 + cL];
#pragma unroll
            for (int reg = 0; reg < 4; ++reg) {
                float v0 = gelu_fast(acc0[reg] + bc);
                float v1 = gelu_fast(acc1[reg] + bc);
                int rl = rfrag + reg;
                int cs = (nt * 16 + cL) ^ ((rl & 7) << 3);
                hA[rl][cs] = f2bf(v0);
                hA[rl + 16][cs] = f2bf(v1);
            }
        }
    }
    __syncthreads();

    if (STORE1) {
#pragma unroll
        for (int p = 0; p < 2; ++p) {
            int idx = p * 256 + t;
            int row = idx >> 4;
            int c0 = (idx & 15) * 8;
            int cs0 = c0 ^ ((row & 7) << 3);
            short8 v = *(const short8*)&hA[row][cs0];
            int grow = blockRow + row;
            if (grow < N_NODES)
                *(short8*)((unsigned short*)out1 + (size_t)grow * HID + c0) = v;
        }
    }

    // ---- stage 2: A-frags from hA ----
    short8 c1[2][4];
    const int rA = l & 15;
#pragma unroll
    for (int ks = 0; ks < 4; ++ks) {
        int b0 = (ks * 32 + ko) ^ ((rA & 7) << 3);
        c1[0][ks] = *(const short8*)&hA[rA][b0];
        c1[1][ks] = *(const short8*)&hA[rA + 16][b0];
    }
    if (OBF2) {
        short8 b1v[8];
        const size_t gb = (size_t)(w * 8) * 64 + l;
#pragma unroll
        for (int s = 0; s < 8; ++s)
            b1v[s] = *(const short8*)(B3 + (gb + (size_t)s * 64) * 8);
#pragma unroll
        for (int m = 0; m < 2; ++m) {
            const int nt = w * 2 + m;
            f32x4 acc0 = {0.f, 0.f, 0.f, 0.f};
            f32x4 acc1 = {0.f, 0.f, 0.f, 0.f};
#pragma unroll
            for (int ks = 0; ks < 4; ++ks) {
                const int step = m * 4 + ks;
                acc0 = __builtin_amdgcn_mfma_f32_16x16x32_bf16(c1[0][ks], b1v[step], acc0, 0, 0, 0);
                acc1 = __builtin_amdgcn_mfma_f32_16x16x32_bf16(c1[1][ks], b1v[step], acc1, 0, 0, 0);
            }
            float bc = bias3[nt * 16 + cL];
#pragma unroll
            for (int reg = 0; reg < 4; ++reg) {
                float v0 = acc0[reg] + bc;
                float v1 = acc1[reg] + bc;
                if (ACT2 == 1) { v0 = gelu_fast(v0); v1 = gelu_fast(v1); }
                int rl = rfrag + reg;
                int cs = (nt * 16 + cL) ^ ((rl & 7) << 3);
                hB[rl][cs] = f2bf(v0);
                hB[rl + 16][cs] = f2bf(v1);
            }
        }
        __syncthreads();
#pragma unroll
        for (int p = 0; p < 2; ++p) {
            int idx = p * 256 + t;
            int row = idx >> 4;
            int c0 = (idx & 15) * 8;
            int cs0 = c0 ^ ((row & 7) << 3);
            short8 v = *(const short8*)&hB[row][cs0];
            int grow = blockRow + row;
            if (grow < N_NODES)
                *(short8*)((unsigned short*)out2 + (size_t)grow * (NT2 * 16) + c0) = v;
        }
    } else {
        // f32 out (NT2=16, 256 cols) in two column-halves via fT
#pragma unroll
        for (int h = 0; h < 2; ++h) {
            const int ntb = h * 8 + w * 2;
            short8 b1v[8];
            const size_t gb = (size_t)(ntb * 4) * 64 + l;
#pragma unroll
            for (int s = 0; s < 8; ++s)
                b1v[s] = *(const short8*)(B3 + (gb + (size_t)s * 64) * 8);
#pragma unroll
            for (int m = 0; m < 2; ++m) {
                const int nt = ntb + m;
                f32x4 acc0 = {0.f, 0.f, 0.f, 0.f};
                f32x4 acc1 = {0.f, 0.f, 0.f, 0.f};
#pragma unroll
                for (int ks = 0; ks < 4; ++ks) {
                    const int step = m * 4 + ks;
                    acc0 = __builtin_amdgcn_mfma_f32_16x16x32_bf16(c1[0][ks], b1v[step], acc0, 0, 0, 0);
                    acc1 = __builtin_amdgcn_mfma_f32_16x16x32_bf16(c1[1][ks], b1v[step], acc1, 0, 0, 0);
                }
                float bc = bias3[nt * 16 + cL];
                int ct = (nt - h * 8) * 16 + cL;
#pragma unroll
                for (int reg = 0; reg < 4; ++reg) {
                    float v0 = acc0[reg] + bc;
                    float v1 = acc1[reg] + bc;
                    if (ACT2 == 1) { v0 = gelu_fast(v0); v1 = gelu_fast(v1); }
                    fT[rfrag + reg][ct] = v0;
                    fT[rfrag + reg + 16][ct] = v1;
                }
            }
            __syncthreads();
#pragma unroll
            for (int p = 0; p < 4; ++p) {
                int idx = p * 256 + t;
                int row = idx >> 5;
                int s4 = (idx & 31) * 4;
                float4 v = *(const float4*)&fT[row][s4];
                int grow = blockRow + row;
                if (grow < N_NODES)
                    *(float4*)((float*)out2 + (size_t)grow * 256 + h * 128 + s4) = v;
            }
            __syncthreads();
        }
    }
}

// ---------------------------------------------------------------------------
// Gather segment max over bf16 rows: one wave per node, ushort2 per lane.
// ---------------------------------------------------------------------------
__global__ __launch_bounds__(256) void seg_max_bf(const unsigned short* __restrict__ y,
                                                  const int* __restrict__ csr,
                                                  const int* __restrict__ off,
                                                  const int* __restrict__ deg,
                                                  unsigned short* __restrict__ agg) {
    int n = blockIdx.x * 4 + (threadIdx.x >> 6);
    int lane = threadIdx.x & 63;
    int s = off[n];
    int d = deg[n];
    const unsigned short* yb = y + lane * 2;
    float a0 = 0.f, a1 = 0.f;
    int i = 0;
    for (; i + 4 <= d; i += 4) {
        int s0 = csr[s + i], s1 = csr[s + i + 1], s2 = csr[s + i + 2], s3 = csr[s + i + 3];
        unsigned v0 = *(const unsigned*)(yb + (size_t)s0 * HID);
        unsigned v1 = *(const unsigned*)(yb + (size_t)s1 * HID);
        unsigned v2 = *(const unsigned*)(yb + (size_t)s2 * HID);
        unsigned v3 = *(const unsigned*)(yb + (size_t)s3 * HID);
        a0 = fmaxf(a0, fmaxf(fmaxf(__uint_as_float(v0 << 16), __uint_as_float(v1 << 16)),
                             fmaxf(__uint_as_float(v2 << 16), __uint_as_float(v3 << 16))));
        a1 = fmaxf(a1, fmaxf(fmaxf(__uint_as_float(v0 & 0xffff0000u), __uint_as_float(v1 & 0xffff0000u)),
                             fmaxf(__uint_as_float(v2 & 0xffff0000u), __uint_as_float(v3 & 0xffff0000u))));
    }
    for (; i < d; ++i) {
        int s0 = csr[s + i];
        unsigned v0 = *(const unsigned*)(yb + (size_t)s0 * HID);
        a0 = fmaxf(a0, __uint_as_float(v0 << 16));
        a1 = fmaxf(a1, __uint_as_float(v0 & 0xffff0000u));
    }
    unsigned o = (unsigned)f2bf(a0) | ((unsigned)f2bf(a1) << 16);
    *(unsigned*)(agg + (size_t)n * HID + lane * 2) = o;
}

extern "C" void kernel_launch(void* const* d_in, const int* in_sizes, int n_in,
                              void* d_out, int out_size, void* d_ws, size_t ws_size,
                              hipStream_t stream) {
    const float* x    = (const float*)d_in[0];
    const int*   ei   = (const int*)d_in[1];
    const float* Wp1  = (const float*)d_in[2];
    const float* bp1  = (const float*)d_in[3];
    const float* Wl1  = (const float*)d_in[4];
    const float* bl1  = (const float*)d_in[5];
    const float* Wr1  = (const float*)d_in[6];
    const float* Wp2  = (const float*)d_in[7];
    const float* bp2  = (const float*)d_in[8];
    const float* Wl2  = (const float*)d_in[9];
    const float* bl2  = (const float*)d_in[10];
    const float* Wr2  = (const float*)d_in[11];
    const float* Wlin = (const float*)d_in[12];
    const float* blin = (const float*)d_in[13];
    float* out = (float*)d_out;

    // ws layout (ushort units for bf16 region); wpack hi-only = 131072
    unsigned short* wpack = (unsigned short*)d_ws;
    unsigned short* xbf   = wpack + 131072;
    unsigned short* ybf   = xbf + (size_t)N_NODES * HID;
    unsigned short* aggbf = ybf + (size_t)N_NODES * HID;
    unsigned short* h1bf  = aggbf + (size_t)N_NODES * HID;
    int* deg    = (int*)(h1bf + (size_t)N_NODES * HID);  // 50000
    int* cursor = deg + N_NODES;                          // 4 (zeroed w/ deg)
    int* off    = cursor + 4;                             // 50000
    int* rank   = off + N_NODES;                          // 600000
    int* csr    = rank + N_EDGES;                         // 600000

    const unsigned short* Bp1 = wpack + 0;
    const unsigned short* Bl1 = wpack + 16384;
    const unsigned short* Br1 = wpack + 32768;
    const unsigned short* Bp2 = wpack + 49152;
    const unsigned short* Bl2 = wpack + 65536;
    const unsigned short* Br2 = wpack + 81920;
    const unsigned short* Blin = wpack + 98304;

    const int RB32 = (N_NODES + 31) / 32;   // 1563
    const int NPB  = (N_NODES + 255) / 256; // 196

    // 1. zero deg/cursor (prereq for prep's count role)
    hipLaunchKernelGGL(zero_deg, dim3(49), dim3(256), 0, stream, deg);

    // 2. prep: pack weights | convert x | count+rank (role-split)
    hipLaunchKernelGGL(prep, dim3(PACK_BLOCKS + CVT_BLOCKS + CNT_BLOCKS), dim3(256), 0, stream,
                       x, xbf, Wp1, Wl1, Wr1, Wp2, Wl2, Wr2, Wlin, wpack, ei, deg, rank);

    // 3. offsets
    hipLaunchKernelGGL(build_off, dim3(NPB), dim3(256), 0, stream, deg, off, cursor);

    // 4. combo: csr-fill + edge-echo + lin1 (y1 = xbf@Wp1 + bp1), overlapped
    hipLaunchKernelGGL(combo, dim3(FB + EB4 + LB), dim3(256), 0, stream,
                       ei, off, rank, csr, out + (size_t)N_NODES * 256,
                       xbf, Bp1, bp1, ybf);

    // 5. seg_max layer 1
    hipLaunchKernelGGL(seg_max_bf, dim3(N_NODES / 4), dim3(256), 0, stream,
                       ybf, csr, off, deg, aggbf);

    // 6. fused: h1 = gelu(agg@Wl1 + x@Wr1 + bl1) [store]; y2 = h1@Wp2 + bp2
    hipLaunchKernelGGL((mfma_fused<true, 8, 0, true>), dim3(RB32), dim3(256), 0, stream,
                       aggbf, xbf, Bl1, Br1, bl1, h1bf, Bp2, bp2, ybf);

    // 7. seg_max layer 2
    hipLaunchKernelGGL(seg_max_bf, dim3(N_NODES / 4), dim3(256), 0, stream,
                       ybf, csr, off, deg, aggbf);

    // 8. fused: h2 = gelu(agg@Wl2 + h1@Wr2 + bl2); out = gelu(h2@Wlin + blin) f32
    hipLaunchKernelGGL((mfma_fused<false, 16, 1, false>), dim3(RB32), dim3(256), 0, stream,
                       aggbf, h1bf, Bl2, Br2, bl2, nullptr, Blin, blin, out);
}

// Round 14
// 179.323 us; speedup vs baseline: 1.1204x; 1.0103x over previous
//
#include <hip/hip_runtime.h>

#define N_NODES 50000
#define N_EDGES 600000
#define HID 128

typedef __attribute__((ext_vector_type(8))) short short8;
typedef __attribute__((ext_vector_type(4))) float f32x4;

__device__ __forceinline__ unsigned short f2bf(float f) {
    unsigned u = __float_as_uint(f);
    unsigned r = u + 0x7FFFu + ((u >> 16) & 1u);  // RNE
    return (unsigned short)(r >> 16);
}
__device__ __forceinline__ float bf2f(unsigned short h) {
    return __uint_as_float(((unsigned)h) << 16);
}

// gelu(tanh approx) == x / (1 + exp(-2u)), u = 0.79788456*(x + 0.044715 x^3)
__device__ __forceinline__ float gelu_fast(float x) {
    float u = 0.7978845608028654f * (x + 0.044715f * x * x * x);
    return x / (1.0f + __expf(-2.0f * u));
}

// zero deg+cursor (runs before prep so prep's count-role can atomicAdd)
__global__ void zero_deg(int* __restrict__ zbase) {
    int i = blockIdx.x * 256 + threadIdx.x;
    if (i < 12501) ((int4*)zbase)[i] = make_int4(0, 0, 0, 0);
}

// ---------------------------------------------------------------------------
// prep: role-split {count+rank | x cvt | weight pack} in ONE launch.
// R14: count FIRST — its atomic-latency-bound blocks start early and overlap
// with the streaming cvt/pack roles (R13 had count last -> serial 45.7us tail).
// Pack layout (verified R3-R13): n = nt*16+(lane&15), k = ks*32+(lane>>4)*8+j.
// ---------------------------------------------------------------------------
#define CNT_BLOCKS  2344         // 600000/256
#define CVT_BLOCKS  3125         // 50000*128/8/256
#define PACK_BLOCKS 512          // 6 x 64 + 128 (Wlin)
__global__ void prep(const float* __restrict__ x, unsigned short* __restrict__ xbf,
                     const float* __restrict__ Wp1, const float* __restrict__ Wl1,
                     const float* __restrict__ Wr1, const float* __restrict__ Wp2,
                     const float* __restrict__ Wl2, const float* __restrict__ Wr2,
                     const float* __restrict__ Wlin, unsigned short* __restrict__ wpack,
                     const int* __restrict__ ei, int* __restrict__ deg,
                     int* __restrict__ rank) {
    int b = blockIdx.x;
    if (b < CNT_BLOCKS) {
        int e = b * 256 + threadIdx.x;
        if (e < N_EDGES) {
            int dst = ei[N_EDGES + e];
            rank[e] = atomicAdd(&deg[dst], 1);
        }
    } else if (b < CNT_BLOCKS + CVT_BLOCKS) {
        int tid = (b - CNT_BLOCKS) * 256 + threadIdx.x;
        size_t i8 = (size_t)tid * 8;
        if (i8 >= (size_t)N_NODES * HID) return;
        float4 v0 = *(const float4*)(x + i8);
        float4 v1 = *(const float4*)(x + i8 + 4);
        short8 o;
        o[0] = f2bf(v0.x); o[1] = f2bf(v0.y); o[2] = f2bf(v0.z); o[3] = f2bf(v0.w);
        o[4] = f2bf(v1.x); o[5] = f2bf(v1.y); o[6] = f2bf(v1.z); o[7] = f2bf(v1.w);
        *(short8*)(xbf + i8) = o;
    } else {
        int pb = b - CNT_BLOCKS - CVT_BLOCKS;
        const float* W;
        int base, idx;
        if (pb < 384) {
            int which = pb >> 6;
            switch (which) {
                case 0: W = Wp1; break;
                case 1: W = Wl1; break;
                case 2: W = Wr1; break;
                case 3: W = Wp2; break;
                case 4: W = Wl2; break;
                default: W = Wr2; break;
            }
            base = which * 16384;
            idx = (pb & 63) * 256 + threadIdx.x;
        } else {
            W = Wlin;
            base = 98304;
            idx = (pb - 384) * 256 + threadIdx.x;
        }
        int j = idx & 7;
        int lane = (idx >> 3) & 63;
        int ks = (idx >> 9) & 3;
        int nt = idx >> 11;
        int c = nt * 16 + (lane & 15);
        int k = ks * 32 + (lane >> 4) * 8 + j;
        wpack[base + idx] = f2bf(W[c * 128 + k]);
    }
}

// One-kernel exclusive scan via atomic cursor (order-invariant downstream).
__global__ void build_off(const int* __restrict__ deg, int* __restrict__ off,
                          int* __restrict__ cursor) {
    __shared__ int sm[256];
    __shared__ int base;
    int t = threadIdx.x;
    int i = blockIdx.x * 256 + t;
    int v = (i < N_NODES) ? deg[i] : 0;
    sm[t] = v;
    __syncthreads();
    for (int s = 1; s < 256; s <<= 1) {
        int tv = (t >= s) ? sm[t - s] : 0;
        __syncthreads();
        sm[t] += tv;
        __syncthreads();
    }
    if (t == 255) base = atomicAdd(cursor, sm[255]);
    __syncthreads();
    if (i < N_NODES) off[i] = base + sm[t] - v;
}

// ---------------------------------------------------------------------------
// combo: block-role split {csr-fill | edge echo | lin1} in ONE launch.
// ---------------------------------------------------------------------------
#define FB   2344   // fill blocks (600000/256)
#define EB4  1172   // echo blocks (1200000/4/256)
#define LB   1563   // lin1 blocks (50000/32)
__global__ __launch_bounds__(256, 2) void combo(
        const int* __restrict__ ei, const int* __restrict__ off,
        const int* __restrict__ rank, int* __restrict__ csr,
        float* __restrict__ echo,
        const unsigned short* __restrict__ in1, const unsigned short* __restrict__ B1,
        const float* __restrict__ bias1, unsigned short* __restrict__ out1) {
    int b = blockIdx.x;
    int t = threadIdx.x;
    if (b < FB) {
        int e = b * 256 + t;
        if (e < N_EDGES) {
            int dst = ei[N_EDGES + e];
            csr[off[dst] + rank[e]] = ei[e];
        }
        return;
    }
    if (b < FB + EB4) {
        int idx = (b - FB) * 256 + t;
        int i = idx * 4;
        if (i < 2 * N_EDGES) {
            int4 v = *(const int4*)(ei + i);
            float4 f = make_float4((float)v.x, (float)v.y, (float)v.z, (float)v.w);
            *(float4*)(echo + i) = f;
        }
        return;
    }
    {
        __shared__ alignas(16) unsigned short hA[32][128];
        const int bid = b - FB - EB4;
        const int w = t >> 6;
        const int l = t & 63;
        const int blockRow = bid * 32;

        int r0 = blockRow + (l & 15);
        int r1 = r0 + 16;
        if (r0 > N_NODES - 1) r0 = N_NODES - 1;
        if (r1 > N_NODES - 1) r1 = N_NODES - 1;
        const int ko = (l >> 4) * 8;

        short8 a1[2][4];
#pragma unroll
        for (int ks = 0; ks < 4; ++ks) {
            a1[0][ks] = *(const short8*)(in1 + (size_t)r0 * HID + ks * 32 + ko);
            a1[1][ks] = *(const short8*)(in1 + (size_t)r1 * HID + ks * 32 + ko);
        }
        const int cL = l & 15;
        const int rfrag = (l >> 4) * 4;

        short8 b1v[8];
        const size_t gb = (size_t)(w * 8) * 64 + l;
#pragma unroll
        for (int s = 0; s < 8; ++s)
            b1v[s] = *(const short8*)(B1 + (gb + (size_t)s * 64) * 8);

#pragma unroll
        for (int m = 0; m < 2; ++m) {
            const int nt = w * 2 + m;
            f32x4 acc0 = {0.f, 0.f, 0.f, 0.f};
            f32x4 acc1 = {0.f, 0.f, 0.f, 0.f};
#pragma unroll
            for (int ks = 0; ks < 4; ++ks) {
                const int step = m * 4 + ks;
                acc0 = __builtin_amdgcn_mfma_f32_16x16x32_bf16(a1[0][ks], b1v[step], acc0, 0, 0, 0);
                acc1 = __builtin_amdgcn_mfma_f32_16x16x32_bf16(a1[1][ks], b1v[step], acc1, 0, 0, 0);
            }
            float bc = bias1[nt * 16 + cL];
#pragma unroll
            for (int reg = 0; reg < 4; ++reg) {
                int rl = rfrag + reg;
                int cs = (nt * 16 + cL) ^ ((rl & 7) << 3);
                hA[rl][cs] = f2bf(acc0[reg] + bc);
                hA[rl + 16][cs] = f2bf(acc1[reg] + bc);
            }
        }
        __syncthreads();
#pragma unroll
        for (int p = 0; p < 2; ++p) {
            int idx = p * 256 + t;
            int row = idx >> 4;
            int c0 = (idx & 15) * 8;
            int cs0 = c0 ^ ((row & 7) << 3);
            short8 v = *(const short8*)&hA[row][cs0];
            int grow = blockRow + row;
            if (grow < N_NODES)
                *(short8*)(out1 + (size_t)grow * HID + c0) = v;
        }
    }
}

// ---------------------------------------------------------------------------
// Fused dual-GEMM + second stage (1-term bf16, upfront B loads).
// R14: f32 path uses ONE wide fT[32][260] (all 4 nt-tiles per wave, single
// barrier, one coalesced store pass) instead of two column-half passes.
// ---------------------------------------------------------------------------
template <bool STORE1, int NT2, int ACT2, bool OBF2>
__global__ __launch_bounds__(256, 2) void mfma_fused(
        const unsigned short* __restrict__ in1, const unsigned short* __restrict__ in2,
        const unsigned short* __restrict__ B1, const unsigned short* __restrict__ B2,
        const float* __restrict__ bias1, void* __restrict__ out1,
        const unsigned short* __restrict__ B3, const float* __restrict__ bias3,
        void* __restrict__ out2) {
    __shared__ alignas(16) unsigned short hA[32][128];
    __shared__ alignas(16) unsigned short hB[OBF2 ? 32 : 1][128];
    __shared__ alignas(16) float fT[OBF2 ? 1 : 32][260];

    const int t = threadIdx.x;
    const int w = t >> 6;
    const int l = t & 63;
    const int blockRow = blockIdx.x * 32;

    int r0 = blockRow + (l & 15);
    int r1 = r0 + 16;
    if (r0 > N_NODES - 1) r0 = N_NODES - 1;
    if (r1 > N_NODES - 1) r1 = N_NODES - 1;
    const int ko = (l >> 4) * 8;

    short8 a1[2][4], a2[2][4];
#pragma unroll
    for (int ks = 0; ks < 4; ++ks) {
        a1[0][ks] = *(const short8*)(in1 + (size_t)r0 * HID + ks * 32 + ko);
        a1[1][ks] = *(const short8*)(in1 + (size_t)r1 * HID + ks * 32 + ko);
        a2[0][ks] = *(const short8*)(in2 + (size_t)r0 * HID + ks * 32 + ko);
        a2[1][ks] = *(const short8*)(in2 + (size_t)r1 * HID + ks * 32 + ko);
    }
    const int cL = l & 15;
    const int rfrag = (l >> 4) * 4;

    // ---- stage 1 dual GEMM: all 16 B loads upfront ----
    {
        short8 b1v[8], b2v[8];
        const size_t gb = (size_t)(w * 8) * 64 + l;
#pragma unroll
        for (int s = 0; s < 8; ++s) {
            b1v[s] = *(const short8*)(B1 + (gb + (size_t)s * 64) * 8);
            b2v[s] = *(const short8*)(B2 + (gb + (size_t)s * 64) * 8);
        }
#pragma unroll
        for (int m = 0; m < 2; ++m) {
            const int nt = w * 2 + m;
            f32x4 acc0 = {0.f, 0.f, 0.f, 0.f};
            f32x4 acc1 = {0.f, 0.f, 0.f, 0.f};
#pragma unroll
            for (int ks = 0; ks < 4; ++ks) {
                const int step = m * 4 + ks;
                acc0 = __builtin_amdgcn_mfma_f32_16x16x32_bf16(a1[0][ks], b1v[step], acc0, 0, 0, 0);
                acc1 = __builtin_amdgcn_mfma_f32_16x16x32_bf16(a1[1][ks], b1v[step], acc1, 0, 0, 0);
                acc0 = __builtin_amdgcn_mfma_f32_16x16x32_bf16(a2[0][ks], b2v[step], acc0, 0, 0, 0);
                acc1 = __builtin_amdgcn_mfma_f32_16x16x32_bf16(a2[1][ks], b2v[step], acc1, 0, 0, 0);
            }
            float bc = bias1[nt * 16 + cL];
#pragma unroll
            for (int reg = 0; reg < 4; ++reg) {
                float v0 = gelu_fast(acc0[reg] + bc);
                float v1 = gelu_fast(acc1[reg] + bc);
                int rl = rfrag + reg;
                int cs = (nt * 16 + cL) ^ ((rl & 7) << 3);
                hA[rl][cs] = f2bf(v0);
                hA[rl + 16][cs] = f2bf(v1);
            }
        }
    }
    __syncthreads();

    if (STORE1) {
#pragma unroll
        for (int p = 0; p < 2; ++p) {
            int idx = p * 256 + t;
            int row = idx >> 4;
            int c0 = (idx & 15) * 8;
            int cs0 = c0 ^ ((row & 7) << 3);
            short8 v = *(const short8*)&hA[row][cs0];
            int grow = blockRow + row;
            if (grow < N_NODES)
                *(short8*)((unsigned short*)out1 + (size_t)grow * HID + c0) = v;
        }
    }

    // ---- stage 2: A-frags from hA ----
    short8 c1[2][4];
    const int rA = l & 15;
#pragma unroll
    for (int ks = 0; ks < 4; ++ks) {
        int b0 = (ks * 32 + ko) ^ ((rA & 7) << 3);
        c1[0][ks] = *(const short8*)&hA[rA][b0];
        c1[1][ks] = *(const short8*)&hA[rA + 16][b0];
    }
    if (OBF2) {
        short8 b1v[8];
        const size_t gb = (size_t)(w * 8) * 64 + l;
#pragma unroll
        for (int s = 0; s < 8; ++s)
            b1v[s] = *(const short8*)(B3 + (gb + (size_t)s * 64) * 8);
#pragma unroll
        for (int m = 0; m < 2; ++m) {
            const int nt = w * 2 + m;
            f32x4 acc0 = {0.f, 0.f, 0.f, 0.f};
            f32x4 acc1 = {0.f, 0.f, 0.f, 0.f};
#pragma unroll
            for (int ks = 0; ks < 4; ++ks) {
                const int step = m * 4 + ks;
                acc0 = __builtin_amdgcn_mfma_f32_16x16x32_bf16(c1[0][ks], b1v[step], acc0, 0, 0, 0);
                acc1 = __builtin_amdgcn_mfma_f32_16x16x32_bf16(c1[1][ks], b1v[step], acc1, 0, 0, 0);
            }
            float bc = bias3[nt * 16 + cL];
#pragma unroll
            for (int reg = 0; reg < 4; ++reg) {
                float v0 = acc0[reg] + bc;
                float v1 = acc1[reg] + bc;
                if (ACT2 == 1) { v0 = gelu_fast(v0); v1 = gelu_fast(v1); }
                int rl = rfrag + reg;
                int cs = (nt * 16 + cL) ^ ((rl & 7) << 3);
                hB[rl][cs] = f2bf(v0);
                hB[rl + 16][cs] = f2bf(v1);
            }
        }
        __syncthreads();
#pragma unroll
        for (int p = 0; p < 2; ++p) {
            int idx = p * 256 + t;
            int row = idx >> 4;
            int c0 = (idx & 15) * 8;
            int cs0 = c0 ^ ((row & 7) << 3);
            short8 v = *(const short8*)&hB[row][cs0];
            int grow = blockRow + row;
            if (grow < N_NODES)
                *(short8*)((unsigned short*)out2 + (size_t)grow * (NT2 * 16) + c0) = v;
        }
    } else {
        // f32 out: wave w owns nt in {w*2, w*2+1, 8+w*2, 8+w*2+1}; all 16
        // B-steps upfront; single barrier; one coalesced store pass.
        short8 b1v[16];
        const size_t gb0 = (size_t)(w * 8) * 64 + l;          // steps 8w..8w+7
        const size_t gb1 = (size_t)(32 + w * 8) * 64 + l;     // steps 32+8w..+7
#pragma unroll
        for (int s = 0; s < 8; ++s) {
            b1v[s] = *(const short8*)(B3 + (gb0 + (size_t)s * 64) * 8);
            b1v[8 + s] = *(const short8*)(B3 + (gb1 + (size_t)s * 64) * 8);
        }
#pragma unroll
        for (int mi = 0; mi < 4; ++mi) {
            const int nt = (mi < 2) ? (w * 2 + mi) : (8 + w * 2 + (mi - 2));
            f32x4 acc0 = {0.f, 0.f, 0.f, 0.f};
            f32x4 acc1 = {0.f, 0.f, 0.f, 0.f};
#pragma unroll
            for (int ks = 0; ks < 4; ++ks) {
                const int step = mi * 4 + ks;
                acc0 = __builtin_amdgcn_mfma_f32_16x16x32_bf16(c1[0][ks], b1v[step], acc0, 0, 0, 0);
                acc1 = __builtin_amdgcn_mfma_f32_16x16x32_bf16(c1[1][ks], b1v[step], acc1, 0, 0, 0);
            }
            float bc = bias3[nt * 16 + cL];
            int ct = nt * 16 + cL;
#pragma unroll
            for (int reg = 0; reg < 4; ++reg) {
                float v0 = acc0[reg] + bc;
                float v1 = acc1[reg] + bc;
                if (ACT2 == 1) { v0 = gelu_fast(v0); v1 = gelu_fast(v1); }
                fT[rfrag + reg][ct] = v0;
                fT[rfrag + reg + 16][ct] = v1;
            }
        }
        __syncthreads();
#pragma unroll
        for (int p = 0; p < 8; ++p) {
            int idx = p * 256 + t;
            int row = idx >> 6;
            int s4 = (idx & 63) * 4;
            float4 v = *(const float4*)&fT[row][s4];
            int grow = blockRow + row;
            if (grow < N_NODES)
                *(float4*)((float*)out2 + (size_t)grow * 256 + s4) = v;
        }
    }
}

// ---------------------------------------------------------------------------
// Gather segment max over bf16 rows: one wave per node, ushort2 per lane.
// ---------------------------------------------------------------------------
__global__ __launch_bounds__(256) void seg_max_bf(const unsigned short* __restrict__ y,
                                                  const int* __restrict__ csr,
                                                  const int* __restrict__ off,
                                                  const int* __restrict__ deg,
                                                  unsigned short* __restrict__ agg) {
    int n = blockIdx.x * 4 + (threadIdx.x >> 6);
    int lane = threadIdx.x & 63;
    int s = off[n];
    int d = deg[n];
    const unsigned short* yb = y + lane * 2;
    float a0 = 0.f, a1 = 0.f;
    int i = 0;
    for (; i + 4 <= d; i += 4) {
        int s0 = csr[s + i], s1 = csr[s + i + 1], s2 = csr[s + i + 2], s3 = csr[s + i + 3];
        unsigned v0 = *(const unsigned*)(yb + (size_t)s0 * HID);
        unsigned v1 = *(const unsigned*)(yb + (size_t)s1 * HID);
        unsigned v2 = *(const unsigned*)(yb + (size_t)s2 * HID);
        unsigned v3 = *(const unsigned*)(yb + (size_t)s3 * HID);
        a0 = fmaxf(a0, fmaxf(fmaxf(__uint_as_float(v0 << 16), __uint_as_float(v1 << 16)),
                             fmaxf(__uint_as_float(v2 << 16), __uint_as_float(v3 << 16))));
        a1 = fmaxf(a1, fmaxf(fmaxf(__uint_as_float(v0 & 0xffff0000u), __uint_as_float(v1 & 0xffff0000u)),
                             fmaxf(__uint_as_float(v2 & 0xffff0000u), __uint_as_float(v3 & 0xffff0000u))));
    }
    for (; i < d; ++i) {
        int s0 = csr[s + i];
        unsigned v0 = *(const unsigned*)(yb + (size_t)s0 * HID);
        a0 = fmaxf(a0, __uint_as_float(v0 << 16));
        a1 = fmaxf(a1, __uint_as_float(v0 & 0xffff0000u));
    }
    unsigned o = (unsigned)f2bf(a0) | ((unsigned)f2bf(a1) << 16);
    *(unsigned*)(agg + (size_t)n * HID + lane * 2) = o;
}

extern "C" void kernel_launch(void* const* d_in, const int* in_sizes, int n_in,
                              void* d_out, int out_size, void* d_ws, size_t ws_size,
                              hipStream_t stream) {
    const float* x    = (const float*)d_in[0];
    const int*   ei   = (const int*)d_in[1];
    const float* Wp1  = (const float*)d_in[2];
    const float* bp1  = (const float*)d_in[3];
    const float* Wl1  = (const float*)d_in[4];
    const float* bl1  = (const float*)d_in[5];
    const float* Wr1  = (const float*)d_in[6];
    const float* Wp2  = (const float*)d_in[7];
    const float* bp2  = (const float*)d_in[8];
    const float* Wl2  = (const float*)d_in[9];
    const float* bl2  = (const float*)d_in[10];
    const float* Wr2  = (const float*)d_in[11];
    const float* Wlin = (const float*)d_in[12];
    const float* blin = (const float*)d_in[13];
    float* out = (float*)d_out;

    // ws layout (ushort units for bf16 region); wpack hi-only = 131072
    unsigned short* wpack = (unsigned short*)d_ws;
    unsigned short* xbf   = wpack + 131072;
    unsigned short* ybf   = xbf + (size_t)N_NODES * HID;
    unsigned short* aggbf = ybf + (size_t)N_NODES * HID;
    unsigned short* h1bf  = aggbf + (size_t)N_NODES * HID;
    int* deg    = (int*)(h1bf + (size_t)N_NODES * HID);  // 50000
    int* cursor = deg + N_NODES;                          // 4 (zeroed w/ deg)
    int* off    = cursor + 4;                             // 50000
    int* rank   = off + N_NODES;                          // 600000
    int* csr    = rank + N_EDGES;                         // 600000

    const unsigned short* Bp1 = wpack + 0;
    const unsigned short* Bl1 = wpack + 16384;
    const unsigned short* Br1 = wpack + 32768;
    const unsigned short* Bp2 = wpack + 49152;
    const unsigned short* Bl2 = wpack + 65536;
    const unsigned short* Br2 = wpack + 81920;
    const unsigned short* Blin = wpack + 98304;

    const int RB32 = (N_NODES + 31) / 32;   // 1563
    const int NPB  = (N_NODES + 255) / 256; // 196

    // 1. zero deg/cursor (prereq for prep's count role)
    hipLaunchKernelGGL(zero_deg, dim3(49), dim3(256), 0, stream, deg);

    // 2. prep: count+rank | convert x | pack weights (count first, R14)
    hipLaunchKernelGGL(prep, dim3(CNT_BLOCKS + CVT_BLOCKS + PACK_BLOCKS), dim3(256), 0, stream,
                       x, xbf, Wp1, Wl1, Wr1, Wp2, Wl2, Wr2, Wlin, wpack, ei, deg, rank);

    // 3. offsets
    hipLaunchKernelGGL(build_off, dim3(NPB), dim3(256), 0, stream, deg, off, cursor);

    // 4. combo: csr-fill + edge-echo + lin1 (y1 = xbf@Wp1 + bp1), overlapped
    hipLaunchKernelGGL(combo, dim3(FB + EB4 + LB), dim3(256), 0, stream,
                       ei, off, rank, csr, out + (size_t)N_NODES * 256,
                       xbf, Bp1, bp1, ybf);

    // 5. seg_max layer 1
    hipLaunchKernelGGL(seg_max_bf, dim3(N_NODES / 4), dim3(256), 0, stream,
                       ybf, csr, off, deg, aggbf);

    // 6. fused: h1 = gelu(agg@Wl1 + x@Wr1 + bl1) [store]; y2 = h1@Wp2 + bp2
    hipLaunchKernelGGL((mfma_fused<true, 8, 0, true>), dim3(RB32), dim3(256), 0, stream,
                       aggbf, xbf, Bl1, Br1, bl1, h1bf, Bp2, bp2, ybf);

    // 7. seg_max layer 2
    hipLaunchKernelGGL(seg_max_bf, dim3(N_NODES / 4), dim3(256), 0, stream,
                       ybf, csr, off, deg, aggbf);

    // 8. fused: h2 = gelu(agg@Wl2 + h1@Wr2 + bl2); out = gelu(h2@Wlin + blin) f32
    hipLaunchKernelGGL((mfma_fused<false, 16, 1, false>), dim3(RB32), dim3(256), 0, stream,
                       aggbf, h1bf, Bl2, Br2, bl2, nullptr, Blin, blin, out);
}

// Round 15
// 170.852 us; speedup vs baseline: 1.1760x; 1.0496x over previous
//
#include <hip/hip_runtime.h>

#define N_NODES 50000
#define N_EDGES 600000
#define HID 128

typedef __attribute__((ext_vector_type(8))) short short8;
typedef __attribute__((ext_vector_type(4))) float f32x4;

__device__ __forceinline__ unsigned short f2bf(float f) {
    unsigned u = __float_as_uint(f);
    unsigned r = u + 0x7FFFu + ((u >> 16) & 1u);  // RNE
    return (unsigned short)(r >> 16);
}
__device__ __forceinline__ float bf2f(unsigned short h) {
    return __uint_as_float(((unsigned)h) << 16);
}

// gelu(tanh approx) == x / (1 + exp(-2u)), u = 0.79788456*(x + 0.044715 x^3)
__device__ __forceinline__ float gelu_fast(float x) {
    float u = 0.7978845608028654f * (x + 0.044715f * x * x * x);
    return x / (1.0f + __expf(-2.0f * u));
}

// zero deg+cursor (runs before prep so prep's count-role can atomicAdd)
__global__ void zero_deg(int* __restrict__ zbase) {
    int i = blockIdx.x * 256 + threadIdx.x;
    if (i < 12501) ((int4*)zbase)[i] = make_int4(0, 0, 0, 0);
}

// ---------------------------------------------------------------------------
// prep: role-split {count+rank (2 edges/thr) | x cvt | weight pack}.
// Pack layout (verified R3-R14): n = nt*16+(lane&15), k = ks*32+(lane>>4)*8+j.
// ---------------------------------------------------------------------------
#define CNT_BLOCKS  1172         // 600000/(256*2)
#define CVT_BLOCKS  3125         // 50000*128/8/256
#define PACK_BLOCKS 512          // 6 x 64 + 128 (Wlin)
__global__ void prep(const float* __restrict__ x, unsigned short* __restrict__ xbf,
                     const float* __restrict__ Wp1, const float* __restrict__ Wl1,
                     const float* __restrict__ Wr1, const float* __restrict__ Wp2,
                     const float* __restrict__ Wl2, const float* __restrict__ Wr2,
                     const float* __restrict__ Wlin, unsigned short* __restrict__ wpack,
                     const int* __restrict__ ei, int* __restrict__ deg,
                     int* __restrict__ rank) {
    int b = blockIdx.x;
    if (b < CNT_BLOCKS) {
        int e = b * 512 + threadIdx.x;
#pragma unroll
        for (int q = 0; q < 2; ++q) {
            int ee = e + q * 256;
            if (ee < N_EDGES) {
                int dst = ei[N_EDGES + ee];
                rank[ee] = atomicAdd(&deg[dst], 1);
            }
        }
    } else if (b < CNT_BLOCKS + CVT_BLOCKS) {
        int tid = (b - CNT_BLOCKS) * 256 + threadIdx.x;
        size_t i8 = (size_t)tid * 8;
        if (i8 >= (size_t)N_NODES * HID) return;
        float4 v0 = *(const float4*)(x + i8);
        float4 v1 = *(const float4*)(x + i8 + 4);
        short8 o;
        o[0] = f2bf(v0.x); o[1] = f2bf(v0.y); o[2] = f2bf(v0.z); o[3] = f2bf(v0.w);
        o[4] = f2bf(v1.x); o[5] = f2bf(v1.y); o[6] = f2bf(v1.z); o[7] = f2bf(v1.w);
        *(short8*)(xbf + i8) = o;
    } else {
        int pb = b - CNT_BLOCKS - CVT_BLOCKS;
        const float* W;
        int base, idx;
        if (pb < 384) {
            int which = pb >> 6;
            switch (which) {
                case 0: W = Wp1; break;
                case 1: W = Wl1; break;
                case 2: W = Wr1; break;
                case 3: W = Wp2; break;
                case 4: W = Wl2; break;
                default: W = Wr2; break;
            }
            base = which * 16384;
            idx = (pb & 63) * 256 + threadIdx.x;
        } else {
            W = Wlin;
            base = 98304;
            idx = (pb - 384) * 256 + threadIdx.x;
        }
        int j = idx & 7;
        int lane = (idx >> 3) & 63;
        int ks = (idx >> 9) & 3;
        int nt = idx >> 11;
        int c = nt * 16 + (lane & 15);
        int k = ks * 32 + (lane >> 4) * 8 + j;
        wpack[base + idx] = f2bf(W[c * 128 + k]);
    }
}

// One-kernel exclusive scan via atomic cursor (order-invariant downstream).
__global__ void build_off(const int* __restrict__ deg, int* __restrict__ off,
                          int* __restrict__ cursor) {
    __shared__ int sm[256];
    __shared__ int base;
    int t = threadIdx.x;
    int i = blockIdx.x * 256 + t;
    int v = (i < N_NODES) ? deg[i] : 0;
    sm[t] = v;
    __syncthreads();
    for (int s = 1; s < 256; s <<= 1) {
        int tv = (t >= s) ? sm[t - s] : 0;
        __syncthreads();
        sm[t] += tv;
        __syncthreads();
    }
    if (t == 255) base = atomicAdd(cursor, sm[255]);
    __syncthreads();
    if (i < N_NODES) off[i] = base + sm[t] - v;
}

// ---------------------------------------------------------------------------
// combo: {csr-fill (2 e/thr) | edge echo | lin1 DUAL: y1=x@Wp1+bp1, r1=x@Wr1}
// R15: lin1 emits r1 too (shared A-frags; extra 8 MFMA steps hidden under the
// fill tail). r1 lets fused1's stage-1 drop to a single GEMM.
// ---------------------------------------------------------------------------
#define FB2  1172   // fill blocks (600000/512)
#define EB4  1172   // echo blocks (1200000/4/256)
#define LB   1563   // lin1 blocks (50000/32)
__global__ __launch_bounds__(256, 2) void combo(
        const int* __restrict__ ei, const int* __restrict__ off,
        const int* __restrict__ rank, int* __restrict__ csr,
        float* __restrict__ echo,
        const unsigned short* __restrict__ in1, const unsigned short* __restrict__ B1,
        const unsigned short* __restrict__ B2, const float* __restrict__ bias1,
        unsigned short* __restrict__ out1, unsigned short* __restrict__ rout) {
    int b = blockIdx.x;
    int t = threadIdx.x;
    if (b < FB2) {
        int e = b * 512 + t;
#pragma unroll
        for (int q = 0; q < 2; ++q) {
            int ee = e + q * 256;
            if (ee < N_EDGES) {
                int dst = ei[N_EDGES + ee];
                csr[off[dst] + rank[ee]] = ei[ee];
            }
        }
        return;
    }
    if (b < FB2 + EB4) {
        int idx = (b - FB2) * 256 + t;
        int i = idx * 4;
        if (i < 2 * N_EDGES) {
            int4 v = *(const int4*)(ei + i);
            float4 f = make_float4((float)v.x, (float)v.y, (float)v.z, (float)v.w);
            *(float4*)(echo + i) = f;
        }
        return;
    }
    {
        __shared__ alignas(16) unsigned short hA[32][128];
        __shared__ alignas(16) unsigned short hR[32][128];
        const int bid = b - FB2 - EB4;
        const int w = t >> 6;
        const int l = t & 63;
        const int blockRow = bid * 32;

        int r0 = blockRow + (l & 15);
        int r1 = r0 + 16;
        if (r0 > N_NODES - 1) r0 = N_NODES - 1;
        if (r1 > N_NODES - 1) r1 = N_NODES - 1;
        const int ko = (l >> 4) * 8;

        short8 a1[2][4];
#pragma unroll
        for (int ks = 0; ks < 4; ++ks) {
            a1[0][ks] = *(const short8*)(in1 + (size_t)r0 * HID + ks * 32 + ko);
            a1[1][ks] = *(const short8*)(in1 + (size_t)r1 * HID + ks * 32 + ko);
        }
        const int cL = l & 15;
        const int rfrag = (l >> 4) * 4;

        short8 b1v[8], b2v[8];
        const size_t gb = (size_t)(w * 8) * 64 + l;
#pragma unroll
        for (int s = 0; s < 8; ++s) {
            b1v[s] = *(const short8*)(B1 + (gb + (size_t)s * 64) * 8);
            b2v[s] = *(const short8*)(B2 + (gb + (size_t)s * 64) * 8);
        }

#pragma unroll
        for (int m = 0; m < 2; ++m) {
            const int nt = w * 2 + m;
            f32x4 acc0 = {0.f, 0.f, 0.f, 0.f};
            f32x4 acc1 = {0.f, 0.f, 0.f, 0.f};
            f32x4 acc2 = {0.f, 0.f, 0.f, 0.f};
            f32x4 acc3 = {0.f, 0.f, 0.f, 0.f};
#pragma unroll
            for (int ks = 0; ks < 4; ++ks) {
                const int step = m * 4 + ks;
                acc0 = __builtin_amdgcn_mfma_f32_16x16x32_bf16(a1[0][ks], b1v[step], acc0, 0, 0, 0);
                acc1 = __builtin_amdgcn_mfma_f32_16x16x32_bf16(a1[1][ks], b1v[step], acc1, 0, 0, 0);
                acc2 = __builtin_amdgcn_mfma_f32_16x16x32_bf16(a1[0][ks], b2v[step], acc2, 0, 0, 0);
                acc3 = __builtin_amdgcn_mfma_f32_16x16x32_bf16(a1[1][ks], b2v[step], acc3, 0, 0, 0);
            }
            float bc = bias1[nt * 16 + cL];
#pragma unroll
            for (int reg = 0; reg < 4; ++reg) {
                int rl = rfrag + reg;
                int cs = (nt * 16 + cL) ^ ((rl & 7) << 3);
                hA[rl][cs] = f2bf(acc0[reg] + bc);
                hA[rl + 16][cs] = f2bf(acc1[reg] + bc);
                hR[rl][cs] = f2bf(acc2[reg]);        // r1 = x@Wr1 (no bias)
                hR[rl + 16][cs] = f2bf(acc3[reg]);
            }
        }
        __syncthreads();
#pragma unroll
        for (int p = 0; p < 2; ++p) {
            int idx = p * 256 + t;
            int row = idx >> 4;
            int c0 = (idx & 15) * 8;
            int cs0 = c0 ^ ((row & 7) << 3);
            short8 v = *(const short8*)&hA[row][cs0];
            short8 vr = *(const short8*)&hR[row][cs0];
            int grow = blockRow + row;
            if (grow < N_NODES) {
                *(short8*)(out1 + (size_t)grow * HID + c0) = v;
                *(short8*)(rout + (size_t)grow * HID + c0) = vr;
            }
        }
    }
}

// ---------------------------------------------------------------------------
// Fused kernel (R15): stage1 = gelu(agg@B1 + bias1 + rT) single GEMM with
// LDS-staged r-add; stage2 = DUALOUT ? {out3=h@B3+bias3 (bf16), out4=h@B4
// (bf16, no bias)} : {out3 = gelu(h@B3+bias3) f32 wide} .
// ---------------------------------------------------------------------------
template <bool DUALOUT, int ACT2>
__global__ __launch_bounds__(256, 2) void mfma_fused(
        const unsigned short* __restrict__ in1, const unsigned short* __restrict__ radd,
        const unsigned short* __restrict__ B1, const float* __restrict__ bias1,
        const unsigned short* __restrict__ B3, const float* __restrict__ bias3,
        void* __restrict__ out3,
        const unsigned short* __restrict__ B4, unsigned short* __restrict__ out4) {
    __shared__ alignas(16) unsigned short rT[32][136];   // padded: bank-spread
    __shared__ alignas(16) unsigned short hA[32][128];
    __shared__ alignas(16) unsigned short hB[DUALOUT ? 32 : 1][128];
    __shared__ alignas(16) unsigned short hR[DUALOUT ? 32 : 1][128];
    __shared__ alignas(16) float fT[DUALOUT ? 1 : 32][260];

    const int t = threadIdx.x;
    const int w = t >> 6;
    const int l = t & 63;
    const int blockRow = blockIdx.x * 32;

    // ---- coop-load r tile (linear, padded rows) ----
#pragma unroll
    for (int p = 0; p < 2; ++p) {
        int idx = p * 256 + t;
        int row = idx >> 4;
        int c0 = (idx & 15) * 8;
        int grow = blockRow + row;
        if (grow > N_NODES - 1) grow = N_NODES - 1;
        *(short8*)&rT[row][c0] = *(const short8*)(radd + (size_t)grow * HID + c0);
    }

    int r0 = blockRow + (l & 15);
    int r1 = r0 + 16;
    if (r0 > N_NODES - 1) r0 = N_NODES - 1;
    if (r1 > N_NODES - 1) r1 = N_NODES - 1;
    const int ko = (l >> 4) * 8;

    short8 a1[2][4];
#pragma unroll
    for (int ks = 0; ks < 4; ++ks) {
        a1[0][ks] = *(const short8*)(in1 + (size_t)r0 * HID + ks * 32 + ko);
        a1[1][ks] = *(const short8*)(in1 + (size_t)r1 * HID + ks * 32 + ko);
    }
    const int cL = l & 15;
    const int rfrag = (l >> 4) * 4;

    __syncthreads();  // rT visible to all waves

    // ---- stage 1: single GEMM + r-add + gelu -> hA ----
    {
        short8 b1v[8];
        const size_t gb = (size_t)(w * 8) * 64 + l;
#pragma unroll
        for (int s = 0; s < 8; ++s)
            b1v[s] = *(const short8*)(B1 + (gb + (size_t)s * 64) * 8);
#pragma unroll
        for (int m = 0; m < 2; ++m) {
            const int nt = w * 2 + m;
            f32x4 acc0 = {0.f, 0.f, 0.f, 0.f};
            f32x4 acc1 = {0.f, 0.f, 0.f, 0.f};
#pragma unroll
            for (int ks = 0; ks < 4; ++ks) {
                const int step = m * 4 + ks;
                acc0 = __builtin_amdgcn_mfma_f32_16x16x32_bf16(a1[0][ks], b1v[step], acc0, 0, 0, 0);
                acc1 = __builtin_amdgcn_mfma_f32_16x16x32_bf16(a1[1][ks], b1v[step], acc1, 0, 0, 0);
            }
            float bc = bias1[nt * 16 + cL];
            int ct = nt * 16 + cL;
#pragma unroll
            for (int reg = 0; reg < 4; ++reg) {
                int rl = rfrag + reg;
                float v0 = gelu_fast(acc0[reg] + bc + bf2f(rT[rl][ct]));
                float v1 = gelu_fast(acc1[reg] + bc + bf2f(rT[rl + 16][ct]));
                int cs = ct ^ ((rl & 7) << 3);
                hA[rl][cs] = f2bf(v0);
                hA[rl + 16][cs] = f2bf(v1);
            }
        }
    }
    __syncthreads();

    // ---- stage 2: A-frags from hA ----
    short8 c1[2][4];
    const int rA = l & 15;
#pragma unroll
    for (int ks = 0; ks < 4; ++ks) {
        int b0 = (ks * 32 + ko) ^ ((rA & 7) << 3);
        c1[0][ks] = *(const short8*)&hA[rA][b0];
        c1[1][ks] = *(const short8*)&hA[rA + 16][b0];
    }
    if (DUALOUT) {
        // two bf16 outputs: out3 = h@B3 + bias3 ; out4 = h@B4 (no bias)
        short8 b3v[8], b4v[8];
        const size_t gb = (size_t)(w * 8) * 64 + l;
#pragma unroll
        for (int s = 0; s < 8; ++s) {
            b3v[s] = *(const short8*)(B3 + (gb + (size_t)s * 64) * 8);
            b4v[s] = *(const short8*)(B4 + (gb + (size_t)s * 64) * 8);
        }
#pragma unroll
        for (int m = 0; m < 2; ++m) {
            const int nt = w * 2 + m;
            f32x4 accP0 = {0.f, 0.f, 0.f, 0.f};
            f32x4 accP1 = {0.f, 0.f, 0.f, 0.f};
            f32x4 accR0 = {0.f, 0.f, 0.f, 0.f};
            f32x4 accR1 = {0.f, 0.f, 0.f, 0.f};
#pragma unroll
            for (int ks = 0; ks < 4; ++ks) {
                const int step = m * 4 + ks;
                accP0 = __builtin_amdgcn_mfma_f32_16x16x32_bf16(c1[0][ks], b3v[step], accP0, 0, 0, 0);
                accP1 = __builtin_amdgcn_mfma_f32_16x16x32_bf16(c1[1][ks], b3v[step], accP1, 0, 0, 0);
                accR0 = __builtin_amdgcn_mfma_f32_16x16x32_bf16(c1[0][ks], b4v[step], accR0, 0, 0, 0);
                accR1 = __builtin_amdgcn_mfma_f32_16x16x32_bf16(c1[1][ks], b4v[step], accR1, 0, 0, 0);
            }
            float bc = bias3[nt * 16 + cL];
#pragma unroll
            for (int reg = 0; reg < 4; ++reg) {
                int rl = rfrag + reg;
                int cs = (nt * 16 + cL) ^ ((rl & 7) << 3);
                hB[rl][cs] = f2bf(accP0[reg] + bc);
                hB[rl + 16][cs] = f2bf(accP1[reg] + bc);
                hR[rl][cs] = f2bf(accR0[reg]);
                hR[rl + 16][cs] = f2bf(accR1[reg]);
            }
        }
        __syncthreads();
#pragma unroll
        for (int p = 0; p < 2; ++p) {
            int idx = p * 256 + t;
            int row = idx >> 4;
            int c0 = (idx & 15) * 8;
            int cs0 = c0 ^ ((row & 7) << 3);
            short8 v = *(const short8*)&hB[row][cs0];
            short8 vr = *(const short8*)&hR[row][cs0];
            int grow = blockRow + row;
            if (grow < N_NODES) {
                *(short8*)((unsigned short*)out3 + (size_t)grow * HID + c0) = v;
                *(short8*)(out4 + (size_t)grow * HID + c0) = vr;
            }
        }
    } else {
        // f32 out (256 cols): wave w owns nt {w*2, w*2+1, 8+w*2, 8+w*2+1}
        short8 b1v[16];
        const size_t gb0 = (size_t)(w * 8) * 64 + l;
        const size_t gb1 = (size_t)(32 + w * 8) * 64 + l;
#pragma unroll
        for (int s = 0; s < 8; ++s) {
            b1v[s] = *(const short8*)(B3 + (gb0 + (size_t)s * 64) * 8);
            b1v[8 + s] = *(const short8*)(B3 + (gb1 + (size_t)s * 64) * 8);
        }
#pragma unroll
        for (int mi = 0; mi < 4; ++mi) {
            const int nt = (mi < 2) ? (w * 2 + mi) : (8 + w * 2 + (mi - 2));
            f32x4 acc0 = {0.f, 0.f, 0.f, 0.f};
            f32x4 acc1 = {0.f, 0.f, 0.f, 0.f};
#pragma unroll
            for (int ks = 0; ks < 4; ++ks) {
                const int step = mi * 4 + ks;
                acc0 = __builtin_amdgcn_mfma_f32_16x16x32_bf16(c1[0][ks], b1v[step], acc0, 0, 0, 0);
                acc1 = __builtin_amdgcn_mfma_f32_16x16x32_bf16(c1[1][ks], b1v[step], acc1, 0, 0, 0);
            }
            float bc = bias3[nt * 16 + cL];
            int ct = nt * 16 + cL;
#pragma unroll
            for (int reg = 0; reg < 4; ++reg) {
                float v0 = acc0[reg] + bc;
                float v1 = acc1[reg] + bc;
                if (ACT2 == 1) { v0 = gelu_fast(v0); v1 = gelu_fast(v1); }
                fT[rfrag + reg][ct] = v0;
                fT[rfrag + reg + 16][ct] = v1;
            }
        }
        __syncthreads();
#pragma unroll
        for (int p = 0; p < 8; ++p) {
            int idx = p * 256 + t;
            int row = idx >> 6;
            int s4 = (idx & 63) * 4;
            float4 v = *(const float4*)&fT[row][s4];
            int grow = blockRow + row;
            if (grow < N_NODES)
                *(float4*)((float*)out3 + (size_t)grow * 256 + s4) = v;
        }
    }
}

// ---------------------------------------------------------------------------
// Gather segment max over bf16 rows: one wave per node, ushort2 per lane.
// ---------------------------------------------------------------------------
__global__ __launch_bounds__(256) void seg_max_bf(const unsigned short* __restrict__ y,
                                                  const int* __restrict__ csr,
                                                  const int* __restrict__ off,
                                                  const int* __restrict__ deg,
                                                  unsigned short* __restrict__ agg) {
    int n = blockIdx.x * 4 + (threadIdx.x >> 6);
    int lane = threadIdx.x & 63;
    int s = off[n];
    int d = deg[n];
    const unsigned short* yb = y + lane * 2;
    float a0 = 0.f, a1 = 0.f;
    int i = 0;
    for (; i + 4 <= d; i += 4) {
        int s0 = csr[s + i], s1 = csr[s + i + 1], s2 = csr[s + i + 2], s3 = csr[s + i + 3];
        unsigned v0 = *(const unsigned*)(yb + (size_t)s0 * HID);
        unsigned v1 = *(const unsigned*)(yb + (size_t)s1 * HID);
        unsigned v2 = *(const unsigned*)(yb + (size_t)s2 * HID);
        unsigned v3 = *(const unsigned*)(yb + (size_t)s3 * HID);
        a0 = fmaxf(a0, fmaxf(fmaxf(__uint_as_float(v0 << 16), __uint_as_float(v1 << 16)),
                             fmaxf(__uint_as_float(v2 << 16), __uint_as_float(v3 << 16))));
        a1 = fmaxf(a1, fmaxf(fmaxf(__uint_as_float(v0 & 0xffff0000u), __uint_as_float(v1 & 0xffff0000u)),
                             fmaxf(__uint_as_float(v2 & 0xffff0000u), __uint_as_float(v3 & 0xffff0000u))));
    }
    for (; i < d; ++i) {
        int s0 = csr[s + i];
        unsigned v0 = *(const unsigned*)(yb + (size_t)s0 * HID);
        a0 = fmaxf(a0, __uint_as_float(v0 << 16));
        a1 = fmaxf(a1, __uint_as_float(v0 & 0xffff0000u));
    }
    unsigned o = (unsigned)f2bf(a0) | ((unsigned)f2bf(a1) << 16);
    *(unsigned*)(agg + (size_t)n * HID + lane * 2) = o;
}

extern "C" void kernel_launch(void* const* d_in, const int* in_sizes, int n_in,
                              void* d_out, int out_size, void* d_ws, size_t ws_size,
                              hipStream_t stream) {
    const float* x    = (const float*)d_in[0];
    const int*   ei   = (const int*)d_in[1];
    const float* Wp1  = (const float*)d_in[2];
    const float* bp1  = (const float*)d_in[3];
    const float* Wl1  = (const float*)d_in[4];
    const float* bl1  = (const float*)d_in[5];
    const float* Wr1  = (const float*)d_in[6];
    const float* Wp2  = (const float*)d_in[7];
    const float* bp2  = (const float*)d_in[8];
    const float* Wl2  = (const float*)d_in[9];
    const float* bl2  = (const float*)d_in[10];
    const float* Wr2  = (const float*)d_in[11];
    const float* Wlin = (const float*)d_in[12];
    const float* blin = (const float*)d_in[13];
    float* out = (float*)d_out;

    // ws layout (ushort units); wpack hi-only = 131072
    unsigned short* wpack = (unsigned short*)d_ws;
    unsigned short* xbf   = wpack + 131072;
    unsigned short* ybf   = xbf + (size_t)N_NODES * HID;   // y1 / y2
    unsigned short* aggbf = ybf + (size_t)N_NODES * HID;   // agg (both layers)
    unsigned short* r1bf  = aggbf + (size_t)N_NODES * HID; // x@Wr1
    unsigned short* r2bf  = r1bf + (size_t)N_NODES * HID;  // h1@Wr2
    int* deg    = (int*)(r2bf + (size_t)N_NODES * HID);    // 50000
    int* cursor = deg + N_NODES;                            // 4 (zeroed w/ deg)
    int* off    = cursor + 4;                               // 50000
    int* rank   = off + N_NODES;                            // 600000
    int* csr    = rank + N_EDGES;                           // 600000

    const unsigned short* Bp1 = wpack + 0;
    const unsigned short* Bl1 = wpack + 16384;
    const unsigned short* Br1 = wpack + 32768;
    const unsigned short* Bp2 = wpack + 49152;
    const unsigned short* Bl2 = wpack + 65536;
    const unsigned short* Br2 = wpack + 81920;
    const unsigned short* Blin = wpack + 98304;

    const int RB32 = (N_NODES + 31) / 32;   // 1563
    const int NPB  = (N_NODES + 255) / 256; // 196

    // 1. zero deg/cursor
    hipLaunchKernelGGL(zero_deg, dim3(49), dim3(256), 0, stream, deg);

    // 2. prep: count+rank | convert x | pack weights
    hipLaunchKernelGGL(prep, dim3(CNT_BLOCKS + CVT_BLOCKS + PACK_BLOCKS), dim3(256), 0, stream,
                       x, xbf, Wp1, Wl1, Wr1, Wp2, Wl2, Wr2, Wlin, wpack, ei, deg, rank);

    // 3. offsets
    hipLaunchKernelGGL(build_off, dim3(NPB), dim3(256), 0, stream, deg, off, cursor);

    // 4. combo: csr-fill + echo + {y1 = x@Wp1+bp1, r1 = x@Wr1}
    hipLaunchKernelGGL(combo, dim3(FB2 + EB4 + LB), dim3(256), 0, stream,
                       ei, off, rank, csr, out + (size_t)N_NODES * 256,
                       xbf, Bp1, Br1, bp1, ybf, r1bf);

    // 5. seg_max layer 1
    hipLaunchKernelGGL(seg_max_bf, dim3(N_NODES / 4), dim3(256), 0, stream,
                       ybf, csr, off, deg, aggbf);

    // 6. fused1: h1 = gelu(agg@Wl1 + bl1 + r1); y2 = h1@Wp2+bp2, r2 = h1@Wr2
    hipLaunchKernelGGL((mfma_fused<true, 0>), dim3(RB32), dim3(256), 0, stream,
                       aggbf, r1bf, Bl1, bl1, Bp2, bp2, ybf, Br2, r2bf);

    // 7. seg_max layer 2
    hipLaunchKernelGGL(seg_max_bf, dim3(N_NODES / 4), dim3(256), 0, stream,
                       ybf, csr, off, deg, aggbf);

    // 8. fused2: h2 = gelu(agg@Wl2 + bl2 + r2); out = gelu(h2@Wlin + blin) f32
    hipLaunchKernelGGL((mfma_fused<false, 1>), dim3(RB32), dim3(256), 0, stream,
                       aggbf, r2bf, Bl2, bl2, Blin, blin, out, nullptr, nullptr);
}